// Round 12
// baseline (1085.746 us; speedup 1.0000x reference)
//
#include <hip/hip_runtime.h>
#include <hip/hip_bf16.h>

#define N_NODES 100000
#define NPAD    100096   // 782 * 128
#define N_EDGES 1600000
#define HDIM 128
#define NLAYERS 4
#define NGRAPH 256
#define ENCDIM 256
#define EPS_BN 1e-5f

typedef __attribute__((ext_vector_type(8))) short bf16x8;
typedef __attribute__((ext_vector_type(4))) float f32x4;

__device__ __forceinline__ unsigned short f2bf(float v) {
    unsigned int u = __float_as_uint(v);
    u += 0x7FFFu + ((u >> 16) & 1u);
    return (unsigned short)(u >> 16);
}
__device__ __forceinline__ float bf2f(unsigned int lo16) {
    return __uint_as_float(lo16 << 16);
}

// ---------------- CSR build ----------------
__global__ void k_count(const int* __restrict__ dst, int* __restrict__ cnt) {
    int e = blockIdx.x * 256 + threadIdx.x;
    if (e < N_EDGES) atomicAdd(&cnt[dst[e]], 1);
}

__global__ void k_dinv(const int* __restrict__ cnt, float* __restrict__ dinv) {
    int n = blockIdx.x * 256 + threadIdx.x;
    if (n < N_NODES) dinv[n] = rsqrtf((float)cnt[n] + 1.0f);
}

__global__ void k_scan_block(const int* __restrict__ cnt, int* __restrict__ excl,
                             int* __restrict__ bsums) {
    __shared__ int s[256];
    int t = threadIdx.x;
    int i = blockIdx.x * 256 + t;
    int v = (i < N_NODES) ? cnt[i] : 0;
    s[t] = v;
    __syncthreads();
    for (int off = 1; off < 256; off <<= 1) {
        int x = 0;
        if (t >= off) x = s[t - off];
        __syncthreads();
        if (t >= off) s[t] += x;
        __syncthreads();
    }
    if (i < N_NODES) excl[i] = s[t] - v;
    if (t == 255) bsums[blockIdx.x] = s[255];
}

__global__ void k_scan_sums(int* __restrict__ bsums, int nb) {
    __shared__ int s[512];
    int t = threadIdx.x;
    int v = (t < nb) ? bsums[t] : 0;
    s[t] = v;
    __syncthreads();
    for (int off = 1; off < 512; off <<= 1) {
        int x = 0;
        if (t >= off) x = s[t - off];
        __syncthreads();
        if (t >= off) s[t] += x;
        __syncthreads();
    }
    if (t < nb) bsums[t] = s[t] - v;
}

__global__ void k_scan_add(int* __restrict__ excl, const int* __restrict__ bsums,
                           int* __restrict__ cursor) {
    int i = blockIdx.x * 256 + threadIdx.x;
    if (i < N_NODES) {
        int v = excl[i] + bsums[blockIdx.x];
        excl[i] = v;
        cursor[i] = v;
    }
}

__global__ void k_scatter(const int* __restrict__ src, const int* __restrict__ dst,
                          const float* __restrict__ dinv, int* __restrict__ cursor,
                          int2* __restrict__ csr_ew) {
    int e = blockIdx.x * 256 + threadIdx.x;
    if (e < N_EDGES) {
        int d = dst[e];
        int s = src[e];
        int p = atomicAdd(&cursor[d], 1);
        int2 v;
        v.x = s;
        v.y = __float_as_int(dinv[s] * dinv[d]);
        csr_ew[p] = v;
    }
}

// ---------------- graph bounds via binary search (batch is sorted) ----------------
__global__ void k_gbounds(const int* __restrict__ batch, int* __restrict__ gstart,
                          int* __restrict__ gcnt) {
    __shared__ int s[257];
    int g = threadIdx.x;  // 256 threads
    int lo = 0, hi = N_NODES;
    while (lo < hi) {
        int mid = (lo + hi) >> 1;
        if (batch[mid] < g) lo = mid + 1; else hi = mid;
    }
    s[g] = lo;
    if (g == 255) s[256] = N_NODES;
    __syncthreads();
    gstart[g] = s[g];
    gcnt[g] = s[g + 1] - s[g];
}

// ---------------- weight -> MFMA B-fragment order, split hi/lo ----------------
// F[((nt*4 + ks)*64 + lane)*8 + j] = W[(ks*32 + (lane>>4)*8 + j)*ldw + nt*16 + (lane&15)]
__global__ void k_wfrag(const float* __restrict__ W, int ldw, int ntiles,
                        unsigned short* __restrict__ Fh, unsigned short* __restrict__ Fl) {
    int t = blockIdx.x * 256 + threadIdx.x;
    if (t >= ntiles * 256) return;
    int lane = t & 63, ks = (t >> 6) & 3, nt = t >> 8;
    int r16 = lane & 15, kq = lane >> 4;
    unsigned short h[8], l[8];
#pragma unroll
    for (int j = 0; j < 8; j++) {
        float w = W[(size_t)(ks * 32 + kq * 8 + j) * ldw + nt * 16 + r16];
        unsigned short hh = f2bf(w);
        h[j] = hh;
        l[j] = f2bf(w - bf2f(hh));
    }
    ((ushort4*)(Fh + (size_t)t * 8))[0] = make_ushort4(h[0], h[1], h[2], h[3]);
    ((ushort4*)(Fh + (size_t)t * 8))[1] = make_ushort4(h[4], h[5], h[6], h[7]);
    ((ushort4*)(Fl + (size_t)t * 8))[0] = make_ushort4(l[0], l[1], l[2], l[3]);
    ((ushort4*)(Fl + (size_t)t * 8))[1] = make_ushort4(l[4], l[5], l[6], l[7]);
}

// ---------------- helper: load fp32 A + hi/lo split (layer-0 conv) ----------
__device__ __forceinline__ void load_a_frag(const float* __restrict__ A, size_t row,
                                            bool ok, int kq, int ks,
                                            bf16x8& hv_out, bf16x8& lv_out) {
    float4 v0 = make_float4(0.f, 0.f, 0.f, 0.f);
    float4 v1 = make_float4(0.f, 0.f, 0.f, 0.f);
    if (ok) {
        const float* pa = A + row * 128 + kq * 8 + ks * 32;
        v0 = *(const float4*)pa;
        v1 = *(const float4*)(pa + 4);
    }
    float vv[8] = {v0.x, v0.y, v0.z, v0.w, v1.x, v1.y, v1.z, v1.w};
    bf16x8 hv, lv;
#pragma unroll
    for (int j = 0; j < 8; j++) {
        unsigned short hh = f2bf(vv[j]);
        hv[j] = (short)hh;
        lv[j] = (short)f2bf(vv[j] - bf2f(hh));
    }
    hv_out = hv;
    lv_out = lv;
}

// ------ layer-0 conv GEMM: split-bf16 MFMA, fp32 A (= x), bf16 C out -------
__global__ __launch_bounds__(256) void k_mfma_f32(const float* __restrict__ A,
                                                  const unsigned short* __restrict__ Fh,
                                                  const unsigned short* __restrict__ Fl,
                                                  unsigned short* __restrict__ Cb) {
    int lane = threadIdx.x & 63;
    int wid = threadIdx.x >> 6;
    int r16 = lane & 15, kq = lane >> 4;
    size_t mrow0 = (size_t)blockIdx.x * 128 + wid * 32;

    bf16x8 ah[2][4], al[2][4];
#pragma unroll
    for (int mt = 0; mt < 2; mt++) {
        size_t row = mrow0 + mt * 16 + r16;
        bool ok = row < N_NODES;
#pragma unroll
        for (int ks = 0; ks < 4; ks++)
            load_a_frag(A, row, ok, kq, ks, ah[mt][ks], al[mt][ks]);
    }

    f32x4 acc[2][8];
#pragma unroll
    for (int mt = 0; mt < 2; mt++)
#pragma unroll
        for (int nt = 0; nt < 8; nt++) acc[mt][nt] = (f32x4){0.f, 0.f, 0.f, 0.f};

#pragma unroll
    for (int nt = 0; nt < 8; nt++) {
        const unsigned short* pbh = Fh + ((size_t)nt * 4 * 64 + lane) * 8;
        const unsigned short* pbl = Fl + ((size_t)nt * 4 * 64 + lane) * 8;
        bf16x8 bh[4], bl[4];
#pragma unroll
        for (int ks = 0; ks < 4; ks++) {
            bh[ks] = *reinterpret_cast<const bf16x8*>(pbh + ks * 512);
            bl[ks] = *reinterpret_cast<const bf16x8*>(pbl + ks * 512);
        }
#pragma unroll
        for (int mt = 0; mt < 2; mt++)
#pragma unroll
            for (int ks = 0; ks < 4; ks++) {
                acc[mt][nt] = __builtin_amdgcn_mfma_f32_16x16x32_bf16(ah[mt][ks], bl[ks],
                                                                     acc[mt][nt], 0, 0, 0);
                acc[mt][nt] = __builtin_amdgcn_mfma_f32_16x16x32_bf16(al[mt][ks], bh[ks],
                                                                     acc[mt][nt], 0, 0, 0);
                acc[mt][nt] = __builtin_amdgcn_mfma_f32_16x16x32_bf16(ah[mt][ks], bh[ks],
                                                                     acc[mt][nt], 0, 0, 0);
            }
    }

#pragma unroll
    for (int mt = 0; mt < 2; mt++)
#pragma unroll
        for (int nt = 0; nt < 8; nt++)
#pragma unroll
            for (int r = 0; r < 4; r++) {
                size_t row = mrow0 + mt * 16 + kq * 4 + r;
                Cb[row * 128 + nt * 16 + r16] = f2bf(acc[mt][nt][r]);
            }
}

// ------ layer>=1 conv GEMM: single-bf16 A (pre-BN'd Ubf), split-bf16 W ----------
__global__ __launch_bounds__(256) void k_mfma_bf(const unsigned short* __restrict__ A,
                                                 const unsigned short* __restrict__ Fh,
                                                 const unsigned short* __restrict__ Fl,
                                                 unsigned short* __restrict__ Cb) {
    int lane = threadIdx.x & 63;
    int wid = threadIdx.x >> 6;
    int r16 = lane & 15, kq = lane >> 4;
    size_t mrow0 = (size_t)blockIdx.x * 128 + wid * 32;

    bf16x8 ah[2][4];
#pragma unroll
    for (int mt = 0; mt < 2; mt++) {
        size_t row = mrow0 + mt * 16 + r16;
        bool ok = row < N_NODES;
#pragma unroll
        for (int ks = 0; ks < 4; ks++) {
            if (ok)
                ah[mt][ks] = *reinterpret_cast<const bf16x8*>(
                    A + row * 128 + ks * 32 + kq * 8);
            else
                ah[mt][ks] = (bf16x8){0, 0, 0, 0, 0, 0, 0, 0};
        }
    }

    f32x4 acc[2][8];
#pragma unroll
    for (int mt = 0; mt < 2; mt++)
#pragma unroll
        for (int nt = 0; nt < 8; nt++) acc[mt][nt] = (f32x4){0.f, 0.f, 0.f, 0.f};

#pragma unroll
    for (int nt = 0; nt < 8; nt++) {
        const unsigned short* pbh = Fh + ((size_t)nt * 4 * 64 + lane) * 8;
        const unsigned short* pbl = Fl + ((size_t)nt * 4 * 64 + lane) * 8;
        bf16x8 bh[4], bl[4];
#pragma unroll
        for (int ks = 0; ks < 4; ks++) {
            bh[ks] = *reinterpret_cast<const bf16x8*>(pbh + ks * 512);
            bl[ks] = *reinterpret_cast<const bf16x8*>(pbl + ks * 512);
        }
#pragma unroll
        for (int mt = 0; mt < 2; mt++)
#pragma unroll
            for (int ks = 0; ks < 4; ks++) {
                acc[mt][nt] = __builtin_amdgcn_mfma_f32_16x16x32_bf16(ah[mt][ks], bl[ks],
                                                                     acc[mt][nt], 0, 0, 0);
                acc[mt][nt] = __builtin_amdgcn_mfma_f32_16x16x32_bf16(ah[mt][ks], bh[ks],
                                                                     acc[mt][nt], 0, 0, 0);
            }
    }

#pragma unroll
    for (int mt = 0; mt < 2; mt++)
#pragma unroll
        for (int nt = 0; nt < 8; nt++)
#pragma unroll
            for (int r = 0; r < 4; r++) {
                size_t row = mrow0 + mt * 16 + kq * 4 + r;
                Cb[row * 128 + nt * 16 + r16] = f2bf(acc[mt][nt][r]);
            }
}

// ------ fused K=512 encoder GEMM (pre-BN'd bf16 A, split-bf16 W) + pool ----------
__global__ __launch_bounds__(256) void k_enc_pool(
    const unsigned short* __restrict__ Ub0, const unsigned short* __restrict__ Ub1,
    const unsigned short* __restrict__ Ub2, const unsigned short* __restrict__ Ub3,
    const unsigned short* __restrict__ Fh, const unsigned short* __restrict__ Fl,
    const float* __restrict__ encB, const int* __restrict__ batch,
    float* __restrict__ psum) {
    int lane = threadIdx.x & 63;
    int wid = threadIdx.x >> 6;
    int r16 = lane & 15, kq = lane >> 4;
    size_t brow0 = (size_t)blockIdx.x * 128;
    size_t mrow0 = brow0 + wid * 32;
    int colOff = blockIdx.y * 128;
    int ntBase = blockIdx.y * 8;

    __shared__ int batch_lds[128];
    if (threadIdx.x < 128) {
        size_t row = brow0 + threadIdx.x;
        batch_lds[threadIdx.x] = (row < N_NODES) ? batch[row] : -1;
    }
    __syncthreads();

    f32x4 acc[2][8];
#pragma unroll
    for (int mt = 0; mt < 2; mt++)
#pragma unroll
        for (int nt = 0; nt < 8; nt++) acc[mt][nt] = (f32x4){0.f, 0.f, 0.f, 0.f};

    const unsigned short* Ubs[4] = {Ub0, Ub1, Ub2, Ub3};
#pragma unroll 1
    for (int l = 0; l < 4; l++) {
        const unsigned short* Ub = Ubs[l];
        bf16x8 ah[2][4];
#pragma unroll
        for (int mt = 0; mt < 2; mt++) {
            size_t row = mrow0 + mt * 16 + r16;
            bool ok = row < N_NODES;
#pragma unroll
            for (int ks = 0; ks < 4; ks++) {
                if (ok)
                    ah[mt][ks] = *reinterpret_cast<const bf16x8*>(
                        Ub + row * 128 + ks * 32 + kq * 8);
                else
                    ah[mt][ks] = (bf16x8){0, 0, 0, 0, 0, 0, 0, 0};
            }
        }
        const unsigned short* Fhl = Fh + (size_t)l * 32768;
        const unsigned short* Fll = Fl + (size_t)l * 32768;
#pragma unroll
        for (int nt = 0; nt < 8; nt++) {
            const unsigned short* pbh = Fhl + ((size_t)(ntBase + nt) * 4 * 64 + lane) * 8;
            const unsigned short* pbl = Fll + ((size_t)(ntBase + nt) * 4 * 64 + lane) * 8;
            bf16x8 bh[4], bl[4];
#pragma unroll
            for (int ks = 0; ks < 4; ks++) {
                bh[ks] = *reinterpret_cast<const bf16x8*>(pbh + ks * 512);
                bl[ks] = *reinterpret_cast<const bf16x8*>(pbl + ks * 512);
            }
#pragma unroll
            for (int mt = 0; mt < 2; mt++)
#pragma unroll
                for (int ks = 0; ks < 4; ks++) {
                    acc[mt][nt] = __builtin_amdgcn_mfma_f32_16x16x32_bf16(
                        ah[mt][ks], bl[ks], acc[mt][nt], 0, 0, 0);
                    acc[mt][nt] = __builtin_amdgcn_mfma_f32_16x16x32_bf16(
                        ah[mt][ks], bh[ks], acc[mt][nt], 0, 0, 0);
                }
        }
    }

    // relu(acc + encB), pads zeroed
    float bias[8];
#pragma unroll
    for (int nt = 0; nt < 8; nt++) bias[nt] = encB[colOff + nt * 16 + r16];
#pragma unroll
    for (int mt = 0; mt < 2; mt++)
#pragma unroll
        for (int r = 0; r < 4; r++) {
            bool valid = batch_lds[wid * 32 + mt * 16 + kq * 4 + r] >= 0;
#pragma unroll
            for (int nt = 0; nt < 8; nt++)
                acc[mt][nt][r] = valid ? fmaxf(acc[mt][nt][r] + bias[nt], 0.f) : 0.f;
        }

    // segment pool (batch sorted; block spans few graphs)
    int lastIdx = (int)((N_NODES - 1 - brow0) < 127 ? (N_NODES - 1 - brow0) : 127);
    int g0 = batch_lds[0];
    int g1 = batch_lds[lastIdx];
    __shared__ float sred[4][128];
    for (int g = g0; g <= g1; ++g) {
        float s[8];
#pragma unroll
        for (int nt = 0; nt < 8; nt++) s[nt] = 0.f;
#pragma unroll
        for (int mt = 0; mt < 2; mt++)
#pragma unroll
            for (int r = 0; r < 4; r++) {
                bool m = batch_lds[wid * 32 + mt * 16 + kq * 4 + r] == g;
                if (m) {
#pragma unroll
                    for (int nt = 0; nt < 8; nt++) s[nt] += acc[mt][nt][r];
                }
            }
#pragma unroll
        for (int nt = 0; nt < 8; nt++) {
            s[nt] += __shfl_xor(s[nt], 16);
            s[nt] += __shfl_xor(s[nt], 32);
        }
        if (lane < 16) {
#pragma unroll
            for (int nt = 0; nt < 8; nt++) sred[wid][nt * 16 + r16] = s[nt];
        }
        __syncthreads();
        if (threadIdx.x < 128) {
            float tot = sred[0][threadIdx.x] + sred[1][threadIdx.x] +
                        sred[2][threadIdx.x] + sred[3][threadIdx.x];
            atomicAdd(&psum[(size_t)g * ENCDIM + colOff + threadIdx.x], tot);
        }
        __syncthreads();
    }
}

// ------ aggregation: gather bf16 hw; Ub(raw bf16) <- S * hw + bias ---------------
__global__ __launch_bounds__(256) void k_agg(const unsigned short* __restrict__ hwb,
                                             const int* __restrict__ rs,
                                             const int* __restrict__ cnt,
                                             const int2* __restrict__ csr_ew,
                                             const float* __restrict__ dinv,
                                             const float4* __restrict__ bias4,
                                             unsigned short* __restrict__ Ub) {
    int n = blockIdx.x * 8 + (threadIdx.x >> 5);
    int lane = threadIdx.x & 31;
    if (n >= N_NODES) return;
    float d = dinv[n];
    float dd = d * d;
    ushort4 sb = *(const ushort4*)(hwb + (size_t)n * 128 + lane * 4);
    float4 b = bias4[lane];
    float4 acc;
    acc.x = fmaf(dd, bf2f(sb.x), b.x);
    acc.y = fmaf(dd, bf2f(sb.y), b.y);
    acc.z = fmaf(dd, bf2f(sb.z), b.z);
    acc.w = fmaf(dd, bf2f(sb.w), b.w);
    int s0 = rs[n];
    int c = cnt[n];
    int e = 0;
    for (; e + 8 <= c; e += 8) {
        int2 ee[8];
        ushort4 vv[8];
#pragma unroll
        for (int u = 0; u < 8; u++) ee[u] = csr_ew[s0 + e + u];
#pragma unroll
        for (int u = 0; u < 8; u++)
            vv[u] = *(const ushort4*)(hwb + (size_t)ee[u].x * 128 + lane * 4);
#pragma unroll
        for (int u = 0; u < 8; u++) {
            float w = __int_as_float(ee[u].y);
            acc.x = fmaf(w, bf2f(vv[u].x), acc.x);
            acc.y = fmaf(w, bf2f(vv[u].y), acc.y);
            acc.z = fmaf(w, bf2f(vv[u].z), acc.z);
            acc.w = fmaf(w, bf2f(vv[u].w), acc.w);
        }
    }
    for (; e < c; e++) {
        int2 ee = csr_ew[s0 + e];
        ushort4 v = *(const ushort4*)(hwb + (size_t)ee.x * 128 + lane * 4);
        float w = __int_as_float(ee.y);
        acc.x = fmaf(w, bf2f(v.x), acc.x);
        acc.y = fmaf(w, bf2f(v.y), acc.y);
        acc.z = fmaf(w, bf2f(v.z), acc.z);
        acc.w = fmaf(w, bf2f(v.w), acc.w);
    }
    ushort4 bv;
    bv.x = f2bf(acc.x);
    bv.y = f2bf(acc.y);
    bv.z = f2bf(acc.z);
    bv.w = f2bf(acc.w);
    *(ushort4*)(Ub + (size_t)n * 128 + lane * 4) = bv;
}

// ---------------- BN stats on raw bf16 Ub ----------------
__global__ __launch_bounds__(256) void k_bn_stats(const uint4* __restrict__ Ub4,
                                                  float* __restrict__ sum,
                                                  float* __restrict__ sq) {
    int c = threadIdx.x & 15;   // uint4 column = features 8c..8c+7
    int y = threadIdx.x >> 4;   // 16 row-groups
    float s[8], q[8];
#pragma unroll
    for (int j = 0; j < 8; j++) { s[j] = 0.f; q[j] = 0.f; }
    for (size_t n = (size_t)blockIdx.x * 16 + y; n < N_NODES; n += (size_t)gridDim.x * 16) {
        uint4 v = Ub4[n * 16 + c];
        float a[8];
        a[0] = bf2f(v.x & 0xffffu); a[1] = bf2f(v.x >> 16);
        a[2] = bf2f(v.y & 0xffffu); a[3] = bf2f(v.y >> 16);
        a[4] = bf2f(v.z & 0xffffu); a[5] = bf2f(v.z >> 16);
        a[6] = bf2f(v.w & 0xffffu); a[7] = bf2f(v.w >> 16);
#pragma unroll
        for (int j = 0; j < 8; j++) {
            s[j] += a[j];
            q[j] = fmaf(a[j], a[j], q[j]);
        }
    }
    __shared__ float ls[256][8], lq[256][8];
#pragma unroll
    for (int j = 0; j < 8; j++) {
        ls[threadIdx.x][j] = s[j];
        lq[threadIdx.x][j] = q[j];
    }
    __syncthreads();
    if (y == 0) {
#pragma unroll
        for (int yy = 1; yy < 16; yy++)
#pragma unroll
            for (int j = 0; j < 8; j++) {
                s[j] += ls[yy * 16 + c][j];
                q[j] += lq[yy * 16 + c][j];
            }
#pragma unroll
        for (int j = 0; j < 8; j++) {
            atomicAdd(&sum[c * 8 + j], s[j]);
            atomicAdd(&sq[c * 8 + j], q[j]);
        }
    }
}

__global__ void k_bn_finalize(const float* __restrict__ sum, const float* __restrict__ sq,
                              const float* __restrict__ gamma, const float* __restrict__ beta,
                              float* __restrict__ scale, float* __restrict__ shift) {
    int f = threadIdx.x;
    float mu = sum[f] * (1.0f / N_NODES);
    float var = sq[f] * (1.0f / N_NODES) - mu * mu;
    float s = rsqrtf(var + EPS_BN) * gamma[f];
    scale[f] = s;
    shift[f] = beta[f] - mu * s;
}

// ------ in-place BN+ReLU on bf16 activation buffer -------
__global__ __launch_bounds__(256) void k_bnapply(uint4* __restrict__ Ub4,
                                                 const float* __restrict__ scale,
                                                 const float* __restrict__ shift) {
    size_t i = (size_t)blockIdx.x * 256 + threadIdx.x;  // NPAD*16 uint4s
    int f0 = (int)(i & 15) * 8;
    float4 sc0 = *(const float4*)&scale[f0];
    float4 sc1 = *(const float4*)&scale[f0 + 4];
    float4 sh0 = *(const float4*)&shift[f0];
    float4 sh1 = *(const float4*)&shift[f0 + 4];
    uint4 v = Ub4[i];
    float a0 = fmaxf(fmaf(bf2f(v.x & 0xffffu), sc0.x, sh0.x), 0.f);
    float a1 = fmaxf(fmaf(bf2f(v.x >> 16), sc0.y, sh0.y), 0.f);
    float a2 = fmaxf(fmaf(bf2f(v.y & 0xffffu), sc0.z, sh0.z), 0.f);
    float a3 = fmaxf(fmaf(bf2f(v.y >> 16), sc0.w, sh0.w), 0.f);
    float a4 = fmaxf(fmaf(bf2f(v.z & 0xffffu), sc1.x, sh1.x), 0.f);
    float a5 = fmaxf(fmaf(bf2f(v.z >> 16), sc1.y, sh1.y), 0.f);
    float a6 = fmaxf(fmaf(bf2f(v.w & 0xffffu), sc1.z, sh1.z), 0.f);
    float a7 = fmaxf(fmaf(bf2f(v.w >> 16), sc1.w, sh1.w), 0.f);
    uint4 o;
    o.x = (unsigned int)f2bf(a0) | ((unsigned int)f2bf(a1) << 16);
    o.y = (unsigned int)f2bf(a2) | ((unsigned int)f2bf(a3) << 16);
    o.z = (unsigned int)f2bf(a4) | ((unsigned int)f2bf(a5) << 16);
    o.w = (unsigned int)f2bf(a6) | ((unsigned int)f2bf(a7) << 16);
    Ub4[i] = o;
}

// ---------------- decoder (mean-divide folded in) ----------------
__global__ __launch_bounds__(128) void k_dec(const float* __restrict__ psum,
                                             const int* __restrict__ gcnt,
                                             const float* __restrict__ W1,
                                             const float* __restrict__ b1,
                                             const float* __restrict__ W2,
                                             const float* __restrict__ b2,
                                             float* __restrict__ out) {
    int g = blockIdx.x;
    int j = threadIdx.x;
    float inv = 1.0f / fmaxf((float)gcnt[g], 1.0f);
    const float* p = &psum[g * ENCDIM];
    float acc = b1[j];
    for (int k = 0; k < ENCDIM; k++) acc = fmaf(p[k] * inv, W1[k * 128 + j], acc);
    float h = fmaxf(acc, 0.f) * W2[j];
    for (int off = 32; off; off >>= 1) h += __shfl_down(h, off);
    __shared__ float red[2];
    if ((j & 63) == 0) red[j >> 6] = h;
    __syncthreads();
    if (j == 0) out[g] = red[0] + red[1] + b2[0];
}

extern "C" void kernel_launch(void* const* d_in, const int* in_sizes, int n_in,
                              void* d_out, int out_size, void* d_ws, size_t ws_size,
                              hipStream_t stream) {
    const float* x = (const float*)d_in[0];
    const int* ei = (const int*)d_in[1];
    const int* src = ei;
    const int* dst = ei + N_EDGES;
    const int* batch = (const int*)d_in[2];
    const float* convW = (const float*)d_in[3];
    const float* convB = (const float*)d_in[4];
    const float* gamma = (const float*)d_in[5];
    const float* beta = (const float*)d_in[6];
    const float* encW = (const float*)d_in[7];
    const float* encB = (const float*)d_in[8];
    const float* dW1 = (const float*)d_in[9];
    const float* db1 = (const float*)d_in[10];
    const float* dW2 = (const float*)d_in[11];
    const float* db2 = (const float*)d_in[12];
    float* out = (float*)d_out;

    char* w = (char*)d_ws;
    auto alloc = [&](size_t bytes) {
        char* p = w;
        w += (bytes + 255) & ~(size_t)255;
        return p;
    };
    // workspace budget ~145 MB (well within proven 221 MB envelope)
    int* cnt = (int*)alloc((size_t)N_NODES * 4);
    int* rs = (int*)alloc((size_t)N_NODES * 4);
    int* cursor = (int*)alloc((size_t)N_NODES * 4);
    int* bsums = (int*)alloc(512 * 4);
    float* dinv = (float*)alloc((size_t)N_NODES * 4);
    int2* csr_ew = (int2*)alloc((size_t)N_EDGES * 8);
    unsigned short* B = (unsigned short*)alloc((size_t)NPAD * HDIM * 2);  // hw bf16
    unsigned short* Ubf[NLAYERS];                                  // agg out (bf16)
    for (int l = 0; l < NLAYERS; l++)
        Ubf[l] = (unsigned short*)alloc((size_t)NPAD * HDIM * 2);
    unsigned short* convWfh = (unsigned short*)alloc((size_t)NLAYERS * 16384 * 2);
    unsigned short* convWfl = (unsigned short*)alloc((size_t)NLAYERS * 16384 * 2);
    unsigned short* encWfh = (unsigned short*)alloc((size_t)NLAYERS * 32768 * 2);
    unsigned short* encWfl = (unsigned short*)alloc((size_t)NLAYERS * 32768 * 2);
    float* bnsumAll = (float*)alloc(NLAYERS * 128 * 4);
    float* bnsqAll = (float*)alloc(NLAYERS * 128 * 4);
    float* bnscaleAll = (float*)alloc(NLAYERS * 128 * 4);
    float* bnshiftAll = (float*)alloc(NLAYERS * 128 * 4);
    int* gcnt = (int*)alloc(256 * 4);
    int* gstart = (int*)alloc(256 * 4);
    float* psum = (float*)alloc(256 * 256 * 4);

    // zero init (one batch)
    hipMemsetAsync(cnt, 0, (size_t)N_NODES * 4, stream);
    hipMemsetAsync(bnsumAll, 0, NLAYERS * 128 * 4, stream);
    hipMemsetAsync(bnsqAll, 0, NLAYERS * 128 * 4, stream);
    hipMemsetAsync(psum, 0, 256 * 256 * 4, stream);

    // CSR build + degree normalization
    k_count<<<(N_EDGES + 255) / 256, 256, 0, stream>>>(dst, cnt);
    k_dinv<<<(N_NODES + 255) / 256, 256, 0, stream>>>(cnt, dinv);
    int nb = (N_NODES + 255) / 256;  // 391
    k_scan_block<<<nb, 256, 0, stream>>>(cnt, rs, bsums);
    k_scan_sums<<<1, 512, 0, stream>>>(bsums, nb);
    k_scan_add<<<nb, 256, 0, stream>>>(rs, bsums, cursor);
    k_scatter<<<(N_EDGES + 255) / 256, 256, 0, stream>>>(src, dst, dinv, cursor, csr_ew);
    k_gbounds<<<1, 256, 0, stream>>>(batch, gstart, gcnt);

    // weight fragment permute + split (tiny)
    for (int l = 0; l < NLAYERS; l++) {
        k_wfrag<<<8, 256, 0, stream>>>(convW + (size_t)l * 16384, 128, 8,
                                       convWfh + (size_t)l * 16384,
                                       convWfl + (size_t)l * 16384);
        k_wfrag<<<16, 256, 0, stream>>>(encW + (size_t)l * 128 * 256, 256, 16,
                                        encWfh + (size_t)l * 32768,
                                        encWfl + (size_t)l * 32768);
    }

    for (int l = 0; l < NLAYERS; l++) {
        // hw(bf16) = h @ convW_l  (h = x fp32 for l=0; else pre-BN'd bf16 Ubf[l-1])
        if (l == 0)
            k_mfma_f32<<<NPAD / 128, 256, 0, stream>>>(
                x, convWfh + (size_t)l * 16384, convWfl + (size_t)l * 16384, B);
        else
            k_mfma_bf<<<NPAD / 128, 256, 0, stream>>>(
                Ubf[l - 1], convWfh + (size_t)l * 16384, convWfl + (size_t)l * 16384, B);
        // aggregate (bf16 gather) + bias -> Ubf[l] (raw bf16)
        k_agg<<<N_NODES / 8, 256, 0, stream>>>(B, rs, cnt, csr_ew, dinv,
                                               (const float4*)(convB + l * 128), Ubf[l]);
        // BN stats on raw bf16 + scale/shift
        k_bn_stats<<<512, 256, 0, stream>>>((const uint4*)Ubf[l], bnsumAll + l * 128,
                                            bnsqAll + l * 128);
        k_bn_finalize<<<1, 128, 0, stream>>>(bnsumAll + l * 128, bnsqAll + l * 128,
                                             gamma + l * 128, beta + l * 128,
                                             bnscaleAll + l * 128, bnshiftAll + l * 128);
        // in-place BN+ReLU on Ubf[l] (feeds next conv AND encoder)
        k_bnapply<<<NPAD * 16 / 256, 256, 0, stream>>>((uint4*)Ubf[l],
                                                       bnscaleAll + l * 128,
                                                       bnshiftAll + l * 128);
    }

    // fused K=512 encoder GEMM + bias + ReLU + segment pool
    k_enc_pool<<<dim3(NPAD / 128, 2), 256, 0, stream>>>(
        Ubf[0], Ubf[1], Ubf[2], Ubf[3], encWfh, encWfl, encB, batch, psum);
    k_dec<<<256, 128, 0, stream>>>(psum, gcnt, dW1, db1, dW2, db2, out);
}

// Round 13
// 858.536 us; speedup vs baseline: 1.2646x; 1.2646x over previous
//
#include <hip/hip_runtime.h>
#include <hip/hip_bf16.h>

#define N_NODES 100000
#define NPAD    100096   // 782 * 128
#define N_EDGES 1600000
#define HDIM 128
#define NLAYERS 4
#define NGRAPH 256
#define ENCDIM 256
#define EPS_BN 1e-5f
#define BN_BLOCKS 512

typedef __attribute__((ext_vector_type(8))) short bf16x8;
typedef __attribute__((ext_vector_type(4))) float f32x4;

__device__ __forceinline__ unsigned short f2bf(float v) {
    unsigned int u = __float_as_uint(v);
    u += 0x7FFFu + ((u >> 16) & 1u);
    return (unsigned short)(u >> 16);
}
__device__ __forceinline__ float bf2f(unsigned int lo16) {
    return __uint_as_float(lo16 << 16);
}

// ---------------- CSR build ----------------
__global__ void k_count(const int* __restrict__ dst, int* __restrict__ cnt) {
    int e = blockIdx.x * 256 + threadIdx.x;
    if (e < N_EDGES) atomicAdd(&cnt[dst[e]], 1);
}

__global__ void k_dinv(const int* __restrict__ cnt, float* __restrict__ dinv) {
    int n = blockIdx.x * 256 + threadIdx.x;
    if (n < N_NODES) dinv[n] = rsqrtf((float)cnt[n] + 1.0f);
}

__global__ void k_scan_block(const int* __restrict__ cnt, int* __restrict__ excl,
                             int* __restrict__ bsums) {
    __shared__ int s[256];
    int t = threadIdx.x;
    int i = blockIdx.x * 256 + t;
    int v = (i < N_NODES) ? cnt[i] : 0;
    s[t] = v;
    __syncthreads();
    for (int off = 1; off < 256; off <<= 1) {
        int x = 0;
        if (t >= off) x = s[t - off];
        __syncthreads();
        if (t >= off) s[t] += x;
        __syncthreads();
    }
    if (i < N_NODES) excl[i] = s[t] - v;
    if (t == 255) bsums[blockIdx.x] = s[255];
}

__global__ void k_scan_sums(int* __restrict__ bsums, int nb) {
    __shared__ int s[512];
    int t = threadIdx.x;
    int v = (t < nb) ? bsums[t] : 0;
    s[t] = v;
    __syncthreads();
    for (int off = 1; off < 512; off <<= 1) {
        int x = 0;
        if (t >= off) x = s[t - off];
        __syncthreads();
        if (t >= off) s[t] += x;
        __syncthreads();
    }
    if (t < nb) bsums[t] = s[t] - v;
}

__global__ void k_scan_add(int* __restrict__ excl, const int* __restrict__ bsums,
                           int* __restrict__ cursor) {
    int i = blockIdx.x * 256 + threadIdx.x;
    if (i < N_NODES) {
        int v = excl[i] + bsums[blockIdx.x];
        excl[i] = v;
        cursor[i] = v;
    }
}

__global__ void k_scatter(const int* __restrict__ src, const int* __restrict__ dst,
                          const float* __restrict__ dinv, int* __restrict__ cursor,
                          int2* __restrict__ csr_ew) {
    int e = blockIdx.x * 256 + threadIdx.x;
    if (e < N_EDGES) {
        int d = dst[e];
        int s = src[e];
        int p = atomicAdd(&cursor[d], 1);
        int2 v;
        v.x = s;
        v.y = __float_as_int(dinv[s] * dinv[d]);
        csr_ew[p] = v;
    }
}

// ---------------- graph bounds via binary search (batch is sorted) ----------------
__global__ void k_gbounds(const int* __restrict__ batch, int* __restrict__ gstart,
                          int* __restrict__ gcnt) {
    __shared__ int s[257];
    int g = threadIdx.x;  // 256 threads
    int lo = 0, hi = N_NODES;
    while (lo < hi) {
        int mid = (lo + hi) >> 1;
        if (batch[mid] < g) lo = mid + 1; else hi = mid;
    }
    s[g] = lo;
    if (g == 255) s[256] = N_NODES;
    __syncthreads();
    gstart[g] = s[g];
    gcnt[g] = s[g + 1] - s[g];
}

// ---------------- weight -> MFMA B-fragment order, split hi/lo ----------------
// F[((nt*4 + ks)*64 + lane)*8 + j] = W[(ks*32 + (lane>>4)*8 + j)*ldw + nt*16 + (lane&15)]
__global__ void k_wfrag(const float* __restrict__ W, int ldw, int ntiles,
                        unsigned short* __restrict__ Fh, unsigned short* __restrict__ Fl) {
    int t = blockIdx.x * 256 + threadIdx.x;
    if (t >= ntiles * 256) return;
    int lane = t & 63, ks = (t >> 6) & 3, nt = t >> 8;
    int r16 = lane & 15, kq = lane >> 4;
    unsigned short h[8], l[8];
#pragma unroll
    for (int j = 0; j < 8; j++) {
        float w = W[(size_t)(ks * 32 + kq * 8 + j) * ldw + nt * 16 + r16];
        unsigned short hh = f2bf(w);
        h[j] = hh;
        l[j] = f2bf(w - bf2f(hh));
    }
    ((ushort4*)(Fh + (size_t)t * 8))[0] = make_ushort4(h[0], h[1], h[2], h[3]);
    ((ushort4*)(Fh + (size_t)t * 8))[1] = make_ushort4(h[4], h[5], h[6], h[7]);
    ((ushort4*)(Fl + (size_t)t * 8))[0] = make_ushort4(l[0], l[1], l[2], l[3]);
    ((ushort4*)(Fl + (size_t)t * 8))[1] = make_ushort4(l[4], l[5], l[6], l[7]);
}

// ---------------- helper: load fp32 A + hi/lo split (layer-0 conv) ----------
__device__ __forceinline__ void load_a_frag(const float* __restrict__ A, size_t row,
                                            bool ok, int kq, int ks,
                                            bf16x8& hv_out, bf16x8& lv_out) {
    float4 v0 = make_float4(0.f, 0.f, 0.f, 0.f);
    float4 v1 = make_float4(0.f, 0.f, 0.f, 0.f);
    if (ok) {
        const float* pa = A + row * 128 + kq * 8 + ks * 32;
        v0 = *(const float4*)pa;
        v1 = *(const float4*)(pa + 4);
    }
    float vv[8] = {v0.x, v0.y, v0.z, v0.w, v1.x, v1.y, v1.z, v1.w};
    bf16x8 hv, lv;
#pragma unroll
    for (int j = 0; j < 8; j++) {
        unsigned short hh = f2bf(vv[j]);
        hv[j] = (short)hh;
        lv[j] = (short)f2bf(vv[j] - bf2f(hh));
    }
    hv_out = hv;
    lv_out = lv;
}

// ------ layer-0 conv GEMM: split-bf16 MFMA, fp32 A (= x), bf16 C out -------
__global__ __launch_bounds__(256) void k_mfma_f32(const float* __restrict__ A,
                                                  const unsigned short* __restrict__ Fh,
                                                  const unsigned short* __restrict__ Fl,
                                                  unsigned short* __restrict__ Cb) {
    int lane = threadIdx.x & 63;
    int wid = threadIdx.x >> 6;
    int r16 = lane & 15, kq = lane >> 4;
    size_t mrow0 = (size_t)blockIdx.x * 128 + wid * 32;

    bf16x8 ah[2][4], al[2][4];
#pragma unroll
    for (int mt = 0; mt < 2; mt++) {
        size_t row = mrow0 + mt * 16 + r16;
        bool ok = row < N_NODES;
#pragma unroll
        for (int ks = 0; ks < 4; ks++)
            load_a_frag(A, row, ok, kq, ks, ah[mt][ks], al[mt][ks]);
    }

    f32x4 acc[2][8];
#pragma unroll
    for (int mt = 0; mt < 2; mt++)
#pragma unroll
        for (int nt = 0; nt < 8; nt++) acc[mt][nt] = (f32x4){0.f, 0.f, 0.f, 0.f};

#pragma unroll
    for (int nt = 0; nt < 8; nt++) {
        const unsigned short* pbh = Fh + ((size_t)nt * 4 * 64 + lane) * 8;
        const unsigned short* pbl = Fl + ((size_t)nt * 4 * 64 + lane) * 8;
        bf16x8 bh[4], bl[4];
#pragma unroll
        for (int ks = 0; ks < 4; ks++) {
            bh[ks] = *reinterpret_cast<const bf16x8*>(pbh + ks * 512);
            bl[ks] = *reinterpret_cast<const bf16x8*>(pbl + ks * 512);
        }
#pragma unroll
        for (int mt = 0; mt < 2; mt++)
#pragma unroll
            for (int ks = 0; ks < 4; ks++) {
                acc[mt][nt] = __builtin_amdgcn_mfma_f32_16x16x32_bf16(ah[mt][ks], bl[ks],
                                                                     acc[mt][nt], 0, 0, 0);
                acc[mt][nt] = __builtin_amdgcn_mfma_f32_16x16x32_bf16(al[mt][ks], bh[ks],
                                                                     acc[mt][nt], 0, 0, 0);
                acc[mt][nt] = __builtin_amdgcn_mfma_f32_16x16x32_bf16(ah[mt][ks], bh[ks],
                                                                     acc[mt][nt], 0, 0, 0);
            }
    }

#pragma unroll
    for (int mt = 0; mt < 2; mt++)
#pragma unroll
        for (int nt = 0; nt < 8; nt++)
#pragma unroll
            for (int r = 0; r < 4; r++) {
                size_t row = mrow0 + mt * 16 + kq * 4 + r;
                Cb[row * 128 + nt * 16 + r16] = f2bf(acc[mt][nt][r]);
            }
}

// ------ layer>=1 conv GEMM: single-bf16 A (pre-BN'd Ubf), split-bf16 W ----------
__global__ __launch_bounds__(256) void k_mfma_bf(const unsigned short* __restrict__ A,
                                                 const unsigned short* __restrict__ Fh,
                                                 const unsigned short* __restrict__ Fl,
                                                 unsigned short* __restrict__ Cb) {
    int lane = threadIdx.x & 63;
    int wid = threadIdx.x >> 6;
    int r16 = lane & 15, kq = lane >> 4;
    size_t mrow0 = (size_t)blockIdx.x * 128 + wid * 32;

    bf16x8 ah[2][4];
#pragma unroll
    for (int mt = 0; mt < 2; mt++) {
        size_t row = mrow0 + mt * 16 + r16;
        bool ok = row < N_NODES;
#pragma unroll
        for (int ks = 0; ks < 4; ks++) {
            if (ok)
                ah[mt][ks] = *reinterpret_cast<const bf16x8*>(
                    A + row * 128 + ks * 32 + kq * 8);
            else
                ah[mt][ks] = (bf16x8){0, 0, 0, 0, 0, 0, 0, 0};
        }
    }

    f32x4 acc[2][8];
#pragma unroll
    for (int mt = 0; mt < 2; mt++)
#pragma unroll
        for (int nt = 0; nt < 8; nt++) acc[mt][nt] = (f32x4){0.f, 0.f, 0.f, 0.f};

#pragma unroll
    for (int nt = 0; nt < 8; nt++) {
        const unsigned short* pbh = Fh + ((size_t)nt * 4 * 64 + lane) * 8;
        const unsigned short* pbl = Fl + ((size_t)nt * 4 * 64 + lane) * 8;
        bf16x8 bh[4], bl[4];
#pragma unroll
        for (int ks = 0; ks < 4; ks++) {
            bh[ks] = *reinterpret_cast<const bf16x8*>(pbh + ks * 512);
            bl[ks] = *reinterpret_cast<const bf16x8*>(pbl + ks * 512);
        }
#pragma unroll
        for (int mt = 0; mt < 2; mt++)
#pragma unroll
            for (int ks = 0; ks < 4; ks++) {
                acc[mt][nt] = __builtin_amdgcn_mfma_f32_16x16x32_bf16(ah[mt][ks], bl[ks],
                                                                     acc[mt][nt], 0, 0, 0);
                acc[mt][nt] = __builtin_amdgcn_mfma_f32_16x16x32_bf16(ah[mt][ks], bh[ks],
                                                                     acc[mt][nt], 0, 0, 0);
            }
    }

#pragma unroll
    for (int mt = 0; mt < 2; mt++)
#pragma unroll
        for (int nt = 0; nt < 8; nt++)
#pragma unroll
            for (int r = 0; r < 4; r++) {
                size_t row = mrow0 + mt * 16 + kq * 4 + r;
                Cb[row * 128 + nt * 16 + r16] = f2bf(acc[mt][nt][r]);
            }
}

// ------ fused K=512 encoder GEMM (pre-BN'd bf16 A, split-bf16 W) + pool ----------
__global__ __launch_bounds__(256) void k_enc_pool(
    const unsigned short* __restrict__ Ub0, const unsigned short* __restrict__ Ub1,
    const unsigned short* __restrict__ Ub2, const unsigned short* __restrict__ Ub3,
    const unsigned short* __restrict__ Fh, const unsigned short* __restrict__ Fl,
    const float* __restrict__ encB, const int* __restrict__ batch,
    float* __restrict__ psum) {
    int lane = threadIdx.x & 63;
    int wid = threadIdx.x >> 6;
    int r16 = lane & 15, kq = lane >> 4;
    size_t brow0 = (size_t)blockIdx.x * 128;
    size_t mrow0 = brow0 + wid * 32;
    int colOff = blockIdx.y * 128;
    int ntBase = blockIdx.y * 8;

    __shared__ int batch_lds[128];
    if (threadIdx.x < 128) {
        size_t row = brow0 + threadIdx.x;
        batch_lds[threadIdx.x] = (row < N_NODES) ? batch[row] : -1;
    }
    __syncthreads();

    f32x4 acc[2][8];
#pragma unroll
    for (int mt = 0; mt < 2; mt++)
#pragma unroll
        for (int nt = 0; nt < 8; nt++) acc[mt][nt] = (f32x4){0.f, 0.f, 0.f, 0.f};

    const unsigned short* Ubs[4] = {Ub0, Ub1, Ub2, Ub3};
#pragma unroll 1
    for (int l = 0; l < 4; l++) {
        const unsigned short* Ub = Ubs[l];
        bf16x8 ah[2][4];
#pragma unroll
        for (int mt = 0; mt < 2; mt++) {
            size_t row = mrow0 + mt * 16 + r16;
            bool ok = row < N_NODES;
#pragma unroll
            for (int ks = 0; ks < 4; ks++) {
                if (ok)
                    ah[mt][ks] = *reinterpret_cast<const bf16x8*>(
                        Ub + row * 128 + ks * 32 + kq * 8);
                else
                    ah[mt][ks] = (bf16x8){0, 0, 0, 0, 0, 0, 0, 0};
            }
        }
        const unsigned short* Fhl = Fh + (size_t)l * 32768;
        const unsigned short* Fll = Fl + (size_t)l * 32768;
#pragma unroll
        for (int nt = 0; nt < 8; nt++) {
            const unsigned short* pbh = Fhl + ((size_t)(ntBase + nt) * 4 * 64 + lane) * 8;
            const unsigned short* pbl = Fll + ((size_t)(ntBase + nt) * 4 * 64 + lane) * 8;
            bf16x8 bh[4], bl[4];
#pragma unroll
            for (int ks = 0; ks < 4; ks++) {
                bh[ks] = *reinterpret_cast<const bf16x8*>(pbh + ks * 512);
                bl[ks] = *reinterpret_cast<const bf16x8*>(pbl + ks * 512);
            }
#pragma unroll
            for (int mt = 0; mt < 2; mt++)
#pragma unroll
                for (int ks = 0; ks < 4; ks++) {
                    acc[mt][nt] = __builtin_amdgcn_mfma_f32_16x16x32_bf16(
                        ah[mt][ks], bl[ks], acc[mt][nt], 0, 0, 0);
                    acc[mt][nt] = __builtin_amdgcn_mfma_f32_16x16x32_bf16(
                        ah[mt][ks], bh[ks], acc[mt][nt], 0, 0, 0);
                }
        }
    }

    // relu(acc + encB), pads zeroed
    float bias[8];
#pragma unroll
    for (int nt = 0; nt < 8; nt++) bias[nt] = encB[colOff + nt * 16 + r16];
#pragma unroll
    for (int mt = 0; mt < 2; mt++)
#pragma unroll
        for (int r = 0; r < 4; r++) {
            bool valid = batch_lds[wid * 32 + mt * 16 + kq * 4 + r] >= 0;
#pragma unroll
            for (int nt = 0; nt < 8; nt++)
                acc[mt][nt][r] = valid ? fmaxf(acc[mt][nt][r] + bias[nt], 0.f) : 0.f;
        }

    // segment pool (batch sorted; block spans few graphs)
    int lastIdx = (int)((N_NODES - 1 - brow0) < 127 ? (N_NODES - 1 - brow0) : 127);
    int g0 = batch_lds[0];
    int g1 = batch_lds[lastIdx];
    __shared__ float sred[4][128];
    for (int g = g0; g <= g1; ++g) {
        float s[8];
#pragma unroll
        for (int nt = 0; nt < 8; nt++) s[nt] = 0.f;
#pragma unroll
        for (int mt = 0; mt < 2; mt++)
#pragma unroll
            for (int r = 0; r < 4; r++) {
                bool m = batch_lds[wid * 32 + mt * 16 + kq * 4 + r] == g;
                if (m) {
#pragma unroll
                    for (int nt = 0; nt < 8; nt++) s[nt] += acc[mt][nt][r];
                }
            }
#pragma unroll
        for (int nt = 0; nt < 8; nt++) {
            s[nt] += __shfl_xor(s[nt], 16);
            s[nt] += __shfl_xor(s[nt], 32);
        }
        if (lane < 16) {
#pragma unroll
            for (int nt = 0; nt < 8; nt++) sred[wid][nt * 16 + r16] = s[nt];
        }
        __syncthreads();
        if (threadIdx.x < 128) {
            float tot = sred[0][threadIdx.x] + sred[1][threadIdx.x] +
                        sred[2][threadIdx.x] + sred[3][threadIdx.x];
            atomicAdd(&psum[(size_t)g * ENCDIM + colOff + threadIdx.x], tot);
        }
        __syncthreads();
    }
}

// ------ aggregation: gather bf16 hw; Ub(raw bf16) <- S * hw + bias ---------------
__global__ __launch_bounds__(256) void k_agg(const unsigned short* __restrict__ hwb,
                                             const int* __restrict__ rs,
                                             const int* __restrict__ cnt,
                                             const int2* __restrict__ csr_ew,
                                             const float* __restrict__ dinv,
                                             const float4* __restrict__ bias4,
                                             unsigned short* __restrict__ Ub) {
    int n = blockIdx.x * 8 + (threadIdx.x >> 5);
    int lane = threadIdx.x & 31;
    if (n >= N_NODES) return;
    float d = dinv[n];
    float dd = d * d;
    ushort4 sb = *(const ushort4*)(hwb + (size_t)n * 128 + lane * 4);
    float4 b = bias4[lane];
    float4 acc;
    acc.x = fmaf(dd, bf2f(sb.x), b.x);
    acc.y = fmaf(dd, bf2f(sb.y), b.y);
    acc.z = fmaf(dd, bf2f(sb.z), b.z);
    acc.w = fmaf(dd, bf2f(sb.w), b.w);
    int s0 = rs[n];
    int c = cnt[n];
    int e = 0;
    for (; e + 8 <= c; e += 8) {
        int2 ee[8];
        ushort4 vv[8];
#pragma unroll
        for (int u = 0; u < 8; u++) ee[u] = csr_ew[s0 + e + u];
#pragma unroll
        for (int u = 0; u < 8; u++)
            vv[u] = *(const ushort4*)(hwb + (size_t)ee[u].x * 128 + lane * 4);
#pragma unroll
        for (int u = 0; u < 8; u++) {
            float w = __int_as_float(ee[u].y);
            acc.x = fmaf(w, bf2f(vv[u].x), acc.x);
            acc.y = fmaf(w, bf2f(vv[u].y), acc.y);
            acc.z = fmaf(w, bf2f(vv[u].z), acc.z);
            acc.w = fmaf(w, bf2f(vv[u].w), acc.w);
        }
    }
    for (; e < c; e++) {
        int2 ee = csr_ew[s0 + e];
        ushort4 v = *(const ushort4*)(hwb + (size_t)ee.x * 128 + lane * 4);
        float w = __int_as_float(ee.y);
        acc.x = fmaf(w, bf2f(v.x), acc.x);
        acc.y = fmaf(w, bf2f(v.y), acc.y);
        acc.z = fmaf(w, bf2f(v.z), acc.z);
        acc.w = fmaf(w, bf2f(v.w), acc.w);
    }
    ushort4 bv;
    bv.x = f2bf(acc.x);
    bv.y = f2bf(acc.y);
    bv.z = f2bf(acc.z);
    bv.w = f2bf(acc.w);
    *(ushort4*)(Ub + (size_t)n * 128 + lane * 4) = bv;
}

// ---------------- BN stats on raw bf16 Ub -> per-block partials (NO atomics) -----
__global__ __launch_bounds__(256) void k_bn_stats(const uint4* __restrict__ Ub4,
                                                  float* __restrict__ part_sum,
                                                  float* __restrict__ part_sq) {
    int c = threadIdx.x & 15;   // uint4 column = features 8c..8c+7
    int y = threadIdx.x >> 4;   // 16 row-groups
    float s[8], q[8];
#pragma unroll
    for (int j = 0; j < 8; j++) { s[j] = 0.f; q[j] = 0.f; }
    for (size_t n = (size_t)blockIdx.x * 16 + y; n < N_NODES;
         n += (size_t)gridDim.x * 16) {
        uint4 v = Ub4[n * 16 + c];
        float a[8];
        a[0] = bf2f(v.x & 0xffffu); a[1] = bf2f(v.x >> 16);
        a[2] = bf2f(v.y & 0xffffu); a[3] = bf2f(v.y >> 16);
        a[4] = bf2f(v.z & 0xffffu); a[5] = bf2f(v.z >> 16);
        a[6] = bf2f(v.w & 0xffffu); a[7] = bf2f(v.w >> 16);
#pragma unroll
        for (int j = 0; j < 8; j++) {
            s[j] += a[j];
            q[j] = fmaf(a[j], a[j], q[j]);
        }
    }
    __shared__ float ls[256][9], lq[256][9];  // +1 pad: no bank conflict
#pragma unroll
    for (int j = 0; j < 8; j++) {
        ls[threadIdx.x][j] = s[j];
        lq[threadIdx.x][j] = q[j];
    }
    __syncthreads();
    if (y == 0) {
#pragma unroll
        for (int yy = 1; yy < 16; yy++)
#pragma unroll
            for (int j = 0; j < 8; j++) {
                s[j] += ls[yy * 16 + c][j];
                q[j] += lq[yy * 16 + c][j];
            }
        // plain coalesced stores of this block's 128-feature partials
#pragma unroll
        for (int j = 0; j < 8; j++) {
            part_sum[(size_t)blockIdx.x * 128 + c * 8 + j] = s[j];
            part_sq[(size_t)blockIdx.x * 128 + c * 8 + j] = q[j];
        }
    }
}

// ------ finalize: reduce per-block partials, compute scale/shift ----------------
__global__ void k_bn_finalize(const float* __restrict__ part_sum,
                              const float* __restrict__ part_sq,
                              const float* __restrict__ gamma,
                              const float* __restrict__ beta,
                              float* __restrict__ scale, float* __restrict__ shift) {
    int f = threadIdx.x;  // 128 threads
    float s = 0.f, q = 0.f;
#pragma unroll 4
    for (int b = 0; b < BN_BLOCKS; b++) {
        s += part_sum[(size_t)b * 128 + f];
        q += part_sq[(size_t)b * 128 + f];
    }
    float mu = s * (1.0f / N_NODES);
    float var = q * (1.0f / N_NODES) - mu * mu;
    float sc = rsqrtf(var + EPS_BN) * gamma[f];
    scale[f] = sc;
    shift[f] = beta[f] - mu * sc;
}

// ------ in-place BN+ReLU on bf16 activation buffer -------
__global__ __launch_bounds__(256) void k_bnapply(uint4* __restrict__ Ub4,
                                                 const float* __restrict__ scale,
                                                 const float* __restrict__ shift) {
    size_t i = (size_t)blockIdx.x * 256 + threadIdx.x;  // NPAD*16 uint4s
    int f0 = (int)(i & 15) * 8;
    float4 sc0 = *(const float4*)&scale[f0];
    float4 sc1 = *(const float4*)&scale[f0 + 4];
    float4 sh0 = *(const float4*)&shift[f0];
    float4 sh1 = *(const float4*)&shift[f0 + 4];
    uint4 v = Ub4[i];
    float a0 = fmaxf(fmaf(bf2f(v.x & 0xffffu), sc0.x, sh0.x), 0.f);
    float a1 = fmaxf(fmaf(bf2f(v.x >> 16), sc0.y, sh0.y), 0.f);
    float a2 = fmaxf(fmaf(bf2f(v.y & 0xffffu), sc0.z, sh0.z), 0.f);
    float a3 = fmaxf(fmaf(bf2f(v.y >> 16), sc0.w, sh0.w), 0.f);
    float a4 = fmaxf(fmaf(bf2f(v.z & 0xffffu), sc1.x, sh1.x), 0.f);
    float a5 = fmaxf(fmaf(bf2f(v.z >> 16), sc1.y, sh1.y), 0.f);
    float a6 = fmaxf(fmaf(bf2f(v.w & 0xffffu), sc1.z, sh1.z), 0.f);
    float a7 = fmaxf(fmaf(bf2f(v.w >> 16), sc1.w, sh1.w), 0.f);
    uint4 o;
    o.x = (unsigned int)f2bf(a0) | ((unsigned int)f2bf(a1) << 16);
    o.y = (unsigned int)f2bf(a2) | ((unsigned int)f2bf(a3) << 16);
    o.z = (unsigned int)f2bf(a4) | ((unsigned int)f2bf(a5) << 16);
    o.w = (unsigned int)f2bf(a6) | ((unsigned int)f2bf(a7) << 16);
    Ub4[i] = o;
}

// ---------------- decoder (mean-divide folded in) ----------------
__global__ __launch_bounds__(128) void k_dec(const float* __restrict__ psum,
                                             const int* __restrict__ gcnt,
                                             const float* __restrict__ W1,
                                             const float* __restrict__ b1,
                                             const float* __restrict__ W2,
                                             const float* __restrict__ b2,
                                             float* __restrict__ out) {
    int g = blockIdx.x;
    int j = threadIdx.x;
    float inv = 1.0f / fmaxf((float)gcnt[g], 1.0f);
    const float* p = &psum[g * ENCDIM];
    float acc = b1[j];
    for (int k = 0; k < ENCDIM; k++) acc = fmaf(p[k] * inv, W1[k * 128 + j], acc);
    float h = fmaxf(acc, 0.f) * W2[j];
    for (int off = 32; off; off >>= 1) h += __shfl_down(h, off);
    __shared__ float red[2];
    if ((j & 63) == 0) red[j >> 6] = h;
    __syncthreads();
    if (j == 0) out[g] = red[0] + red[1] + b2[0];
}

extern "C" void kernel_launch(void* const* d_in, const int* in_sizes, int n_in,
                              void* d_out, int out_size, void* d_ws, size_t ws_size,
                              hipStream_t stream) {
    const float* x = (const float*)d_in[0];
    const int* ei = (const int*)d_in[1];
    const int* src = ei;
    const int* dst = ei + N_EDGES;
    const int* batch = (const int*)d_in[2];
    const float* convW = (const float*)d_in[3];
    const float* convB = (const float*)d_in[4];
    const float* gamma = (const float*)d_in[5];
    const float* beta = (const float*)d_in[6];
    const float* encW = (const float*)d_in[7];
    const float* encB = (const float*)d_in[8];
    const float* dW1 = (const float*)d_in[9];
    const float* db1 = (const float*)d_in[10];
    const float* dW2 = (const float*)d_in[11];
    const float* db2 = (const float*)d_in[12];
    float* out = (float*)d_out;

    char* w = (char*)d_ws;
    auto alloc = [&](size_t bytes) {
        char* p = w;
        w += (bytes + 255) & ~(size_t)255;
        return p;
    };
    // workspace budget ~146 MB (well within proven 221 MB envelope)
    int* cnt = (int*)alloc((size_t)N_NODES * 4);
    int* rs = (int*)alloc((size_t)N_NODES * 4);
    int* cursor = (int*)alloc((size_t)N_NODES * 4);
    int* bsums = (int*)alloc(512 * 4);
    float* dinv = (float*)alloc((size_t)N_NODES * 4);
    int2* csr_ew = (int2*)alloc((size_t)N_EDGES * 8);
    unsigned short* B = (unsigned short*)alloc((size_t)NPAD * HDIM * 2);  // hw bf16
    unsigned short* Ubf[NLAYERS];                                  // agg out (bf16)
    for (int l = 0; l < NLAYERS; l++)
        Ubf[l] = (unsigned short*)alloc((size_t)NPAD * HDIM * 2);
    unsigned short* convWfh = (unsigned short*)alloc((size_t)NLAYERS * 16384 * 2);
    unsigned short* convWfl = (unsigned short*)alloc((size_t)NLAYERS * 16384 * 2);
    unsigned short* encWfh = (unsigned short*)alloc((size_t)NLAYERS * 32768 * 2);
    unsigned short* encWfl = (unsigned short*)alloc((size_t)NLAYERS * 32768 * 2);
    float* part_sum = (float*)alloc((size_t)BN_BLOCKS * 128 * 4);
    float* part_sq = (float*)alloc((size_t)BN_BLOCKS * 128 * 4);
    float* bnscaleAll = (float*)alloc(NLAYERS * 128 * 4);
    float* bnshiftAll = (float*)alloc(NLAYERS * 128 * 4);
    int* gcnt = (int*)alloc(256 * 4);
    int* gstart = (int*)alloc(256 * 4);
    float* psum = (float*)alloc(256 * 256 * 4);

    // zero init
    hipMemsetAsync(cnt, 0, (size_t)N_NODES * 4, stream);
    hipMemsetAsync(psum, 0, 256 * 256 * 4, stream);

    // CSR build + degree normalization
    k_count<<<(N_EDGES + 255) / 256, 256, 0, stream>>>(dst, cnt);
    k_dinv<<<(N_NODES + 255) / 256, 256, 0, stream>>>(cnt, dinv);
    int nb = (N_NODES + 255) / 256;  // 391
    k_scan_block<<<nb, 256, 0, stream>>>(cnt, rs, bsums);
    k_scan_sums<<<1, 512, 0, stream>>>(bsums, nb);
    k_scan_add<<<nb, 256, 0, stream>>>(rs, bsums, cursor);
    k_scatter<<<(N_EDGES + 255) / 256, 256, 0, stream>>>(src, dst, dinv, cursor, csr_ew);
    k_gbounds<<<1, 256, 0, stream>>>(batch, gstart, gcnt);

    // weight fragment permute + split (tiny)
    for (int l = 0; l < NLAYERS; l++) {
        k_wfrag<<<8, 256, 0, stream>>>(convW + (size_t)l * 16384, 128, 8,
                                       convWfh + (size_t)l * 16384,
                                       convWfl + (size_t)l * 16384);
        k_wfrag<<<16, 256, 0, stream>>>(encW + (size_t)l * 128 * 256, 256, 16,
                                        encWfh + (size_t)l * 32768,
                                        encWfl + (size_t)l * 32768);
    }

    for (int l = 0; l < NLAYERS; l++) {
        // hw(bf16) = h @ convW_l  (h = x fp32 for l=0; else pre-BN'd bf16 Ubf[l-1])
        if (l == 0)
            k_mfma_f32<<<NPAD / 128, 256, 0, stream>>>(
                x, convWfh + (size_t)l * 16384, convWfl + (size_t)l * 16384, B);
        else
            k_mfma_bf<<<NPAD / 128, 256, 0, stream>>>(
                Ubf[l - 1], convWfh + (size_t)l * 16384, convWfl + (size_t)l * 16384, B);
        // aggregate (bf16 gather) + bias -> Ubf[l] (raw bf16)
        k_agg<<<N_NODES / 8, 256, 0, stream>>>(B, rs, cnt, csr_ew, dinv,
                                               (const float4*)(convB + l * 128), Ubf[l]);
        // BN stats via per-block partials (no atomics), then finalize
        k_bn_stats<<<BN_BLOCKS, 256, 0, stream>>>((const uint4*)Ubf[l], part_sum, part_sq);
        k_bn_finalize<<<1, 128, 0, stream>>>(part_sum, part_sq,
                                             gamma + l * 128, beta + l * 128,
                                             bnscaleAll + l * 128, bnshiftAll + l * 128);
        // in-place BN+ReLU on Ubf[l] (feeds next conv AND encoder)
        k_bnapply<<<NPAD * 16 / 256, 256, 0, stream>>>((uint4*)Ubf[l],
                                                       bnscaleAll + l * 128,
                                                       bnshiftAll + l * 128);
    }

    // fused K=512 encoder GEMM + bias + ReLU + segment pool
    k_enc_pool<<<dim3(NPAD / 128, 2), 256, 0, stream>>>(
        Ubf[0], Ubf[1], Ubf[2], Ubf[3], encWfh, encWfl, encB, batch, psum);
    k_dec<<<256, 128, 0, stream>>>(psum, gcnt, dW1, db1, dW2, db2, out);
}

// Round 14
// 831.772 us; speedup vs baseline: 1.3053x; 1.0322x over previous
//
#include <hip/hip_runtime.h>
#include <hip/hip_bf16.h>

#define N_NODES 100000
#define NPAD    100096   // 782 * 128
#define N_EDGES 1600000
#define HDIM 128
#define NLAYERS 4
#define NGRAPH 256
#define ENCDIM 256
#define EPS_BN 1e-5f
#define BN_BLOCKS 256

typedef __attribute__((ext_vector_type(8))) short bf16x8;
typedef __attribute__((ext_vector_type(4))) float f32x4;

__device__ __forceinline__ unsigned short f2bf(float v) {
    unsigned int u = __float_as_uint(v);
    u += 0x7FFFu + ((u >> 16) & 1u);
    return (unsigned short)(u >> 16);
}
__device__ __forceinline__ float bf2f(unsigned int lo16) {
    return __uint_as_float(lo16 << 16);
}

// ---------------- CSR build ----------------
// 4 edges/thread: 4 independent atomic chains in flight (latency hiding)
__global__ void k_count(const int* __restrict__ dst, int* __restrict__ cnt) {
    int base = blockIdx.x * 1024 + threadIdx.x;
#pragma unroll
    for (int u = 0; u < 4; u++) {
        int e = base + u * 256;
        if (e < N_EDGES) atomicAdd(&cnt[dst[e]], 1);
    }
}

__global__ void k_dinv(const int* __restrict__ cnt, float* __restrict__ dinv) {
    int n = blockIdx.x * 256 + threadIdx.x;
    if (n < N_NODES) dinv[n] = rsqrtf((float)cnt[n] + 1.0f);
}

__global__ void k_scan_block(const int* __restrict__ cnt, int* __restrict__ excl,
                             int* __restrict__ bsums) {
    __shared__ int s[256];
    int t = threadIdx.x;
    int i = blockIdx.x * 256 + t;
    int v = (i < N_NODES) ? cnt[i] : 0;
    s[t] = v;
    __syncthreads();
    for (int off = 1; off < 256; off <<= 1) {
        int x = 0;
        if (t >= off) x = s[t - off];
        __syncthreads();
        if (t >= off) s[t] += x;
        __syncthreads();
    }
    if (i < N_NODES) excl[i] = s[t] - v;
    if (t == 255) bsums[blockIdx.x] = s[255];
}

__global__ void k_scan_sums(int* __restrict__ bsums, int nb) {
    __shared__ int s[512];
    int t = threadIdx.x;
    int v = (t < nb) ? bsums[t] : 0;
    s[t] = v;
    __syncthreads();
    for (int off = 1; off < 512; off <<= 1) {
        int x = 0;
        if (t >= off) x = s[t - off];
        __syncthreads();
        if (t >= off) s[t] += x;
        __syncthreads();
    }
    if (t < nb) bsums[t] = s[t] - v;
}

__global__ void k_scan_add(int* __restrict__ excl, const int* __restrict__ bsums,
                           int* __restrict__ cursor) {
    int i = blockIdx.x * 256 + threadIdx.x;
    if (i < N_NODES) {
        int v = excl[i] + bsums[blockIdx.x];
        excl[i] = v;
        cursor[i] = v;
    }
}

// 4 edges/thread: batch loads, then products, then atomics, then stores
__global__ void k_scatter(const int* __restrict__ src, const int* __restrict__ dst,
                          const float* __restrict__ dinv, int* __restrict__ cursor,
                          int2* __restrict__ csr_ew) {
    int base = blockIdx.x * 1024 + threadIdx.x;
    int s[4], d[4];
    bool ok[4];
#pragma unroll
    for (int u = 0; u < 4; u++) {
        int e = base + u * 256;
        ok[u] = e < N_EDGES;
        s[u] = ok[u] ? src[e] : 0;
        d[u] = ok[u] ? dst[e] : 0;
    }
    float ww[4];
#pragma unroll
    for (int u = 0; u < 4; u++)
        if (ok[u]) ww[u] = dinv[s[u]] * dinv[d[u]];
    int p[4];
#pragma unroll
    for (int u = 0; u < 4; u++)
        if (ok[u]) p[u] = atomicAdd(&cursor[d[u]], 1);
#pragma unroll
    for (int u = 0; u < 4; u++)
        if (ok[u]) {
            int2 v;
            v.x = s[u];
            v.y = __float_as_int(ww[u]);
            csr_ew[p[u]] = v;
        }
}

// ---------------- graph bounds via binary search (batch is sorted) ----------------
__global__ void k_gbounds(const int* __restrict__ batch, int* __restrict__ gstart,
                          int* __restrict__ gcnt) {
    __shared__ int s[257];
    int g = threadIdx.x;  // 256 threads
    int lo = 0, hi = N_NODES;
    while (lo < hi) {
        int mid = (lo + hi) >> 1;
        if (batch[mid] < g) lo = mid + 1; else hi = mid;
    }
    s[g] = lo;
    if (g == 255) s[256] = N_NODES;
    __syncthreads();
    gstart[g] = s[g];
    gcnt[g] = s[g + 1] - s[g];
}

// ---------------- weight -> MFMA B-fragment order, split hi/lo ----------------
// F[((nt*4 + ks)*64 + lane)*8 + j] = W[(ks*32 + (lane>>4)*8 + j)*ldw + nt*16 + (lane&15)]
__global__ void k_wfrag(const float* __restrict__ W, int ldw, int ntiles,
                        unsigned short* __restrict__ Fh, unsigned short* __restrict__ Fl) {
    int t = blockIdx.x * 256 + threadIdx.x;
    if (t >= ntiles * 256) return;
    int lane = t & 63, ks = (t >> 6) & 3, nt = t >> 8;
    int r16 = lane & 15, kq = lane >> 4;
    unsigned short h[8], l[8];
#pragma unroll
    for (int j = 0; j < 8; j++) {
        float w = W[(size_t)(ks * 32 + kq * 8 + j) * ldw + nt * 16 + r16];
        unsigned short hh = f2bf(w);
        h[j] = hh;
        l[j] = f2bf(w - bf2f(hh));
    }
    ((ushort4*)(Fh + (size_t)t * 8))[0] = make_ushort4(h[0], h[1], h[2], h[3]);
    ((ushort4*)(Fh + (size_t)t * 8))[1] = make_ushort4(h[4], h[5], h[6], h[7]);
    ((ushort4*)(Fl + (size_t)t * 8))[0] = make_ushort4(l[0], l[1], l[2], l[3]);
    ((ushort4*)(Fl + (size_t)t * 8))[1] = make_ushort4(l[4], l[5], l[6], l[7]);
}

// ---------------- helper: load fp32 A + hi/lo split (layer-0 conv) ----------
__device__ __forceinline__ void load_a_frag(const float* __restrict__ A, size_t row,
                                            bool ok, int kq, int ks,
                                            bf16x8& hv_out, bf16x8& lv_out) {
    float4 v0 = make_float4(0.f, 0.f, 0.f, 0.f);
    float4 v1 = make_float4(0.f, 0.f, 0.f, 0.f);
    if (ok) {
        const float* pa = A + row * 128 + kq * 8 + ks * 32;
        v0 = *(const float4*)pa;
        v1 = *(const float4*)(pa + 4);
    }
    float vv[8] = {v0.x, v0.y, v0.z, v0.w, v1.x, v1.y, v1.z, v1.w};
    bf16x8 hv, lv;
#pragma unroll
    for (int j = 0; j < 8; j++) {
        unsigned short hh = f2bf(vv[j]);
        hv[j] = (short)hh;
        lv[j] = (short)f2bf(vv[j] - bf2f(hh));
    }
    hv_out = hv;
    lv_out = lv;
}

// ------ layer-0 conv GEMM: split-bf16 MFMA, fp32 A (= x), bf16 C out -------
__global__ __launch_bounds__(256) void k_mfma_f32(const float* __restrict__ A,
                                                  const unsigned short* __restrict__ Fh,
                                                  const unsigned short* __restrict__ Fl,
                                                  unsigned short* __restrict__ Cb) {
    int lane = threadIdx.x & 63;
    int wid = threadIdx.x >> 6;
    int r16 = lane & 15, kq = lane >> 4;
    size_t mrow0 = (size_t)blockIdx.x * 128 + wid * 32;

    bf16x8 ah[2][4], al[2][4];
#pragma unroll
    for (int mt = 0; mt < 2; mt++) {
        size_t row = mrow0 + mt * 16 + r16;
        bool ok = row < N_NODES;
#pragma unroll
        for (int ks = 0; ks < 4; ks++)
            load_a_frag(A, row, ok, kq, ks, ah[mt][ks], al[mt][ks]);
    }

    f32x4 acc[2][8];
#pragma unroll
    for (int mt = 0; mt < 2; mt++)
#pragma unroll
        for (int nt = 0; nt < 8; nt++) acc[mt][nt] = (f32x4){0.f, 0.f, 0.f, 0.f};

#pragma unroll
    for (int nt = 0; nt < 8; nt++) {
        const unsigned short* pbh = Fh + ((size_t)nt * 4 * 64 + lane) * 8;
        const unsigned short* pbl = Fl + ((size_t)nt * 4 * 64 + lane) * 8;
        bf16x8 bh[4], bl[4];
#pragma unroll
        for (int ks = 0; ks < 4; ks++) {
            bh[ks] = *reinterpret_cast<const bf16x8*>(pbh + ks * 512);
            bl[ks] = *reinterpret_cast<const bf16x8*>(pbl + ks * 512);
        }
#pragma unroll
        for (int mt = 0; mt < 2; mt++)
#pragma unroll
            for (int ks = 0; ks < 4; ks++) {
                acc[mt][nt] = __builtin_amdgcn_mfma_f32_16x16x32_bf16(ah[mt][ks], bl[ks],
                                                                     acc[mt][nt], 0, 0, 0);
                acc[mt][nt] = __builtin_amdgcn_mfma_f32_16x16x32_bf16(al[mt][ks], bh[ks],
                                                                     acc[mt][nt], 0, 0, 0);
                acc[mt][nt] = __builtin_amdgcn_mfma_f32_16x16x32_bf16(ah[mt][ks], bh[ks],
                                                                     acc[mt][nt], 0, 0, 0);
            }
    }

#pragma unroll
    for (int mt = 0; mt < 2; mt++)
#pragma unroll
        for (int nt = 0; nt < 8; nt++)
#pragma unroll
            for (int r = 0; r < 4; r++) {
                size_t row = mrow0 + mt * 16 + kq * 4 + r;
                Cb[row * 128 + nt * 16 + r16] = f2bf(acc[mt][nt][r]);
            }
}

// ------ layer>=1 conv GEMM: single-bf16 A (pre-BN'd Ubf), split-bf16 W ----------
__global__ __launch_bounds__(256) void k_mfma_bf(const unsigned short* __restrict__ A,
                                                 const unsigned short* __restrict__ Fh,
                                                 const unsigned short* __restrict__ Fl,
                                                 unsigned short* __restrict__ Cb) {
    int lane = threadIdx.x & 63;
    int wid = threadIdx.x >> 6;
    int r16 = lane & 15, kq = lane >> 4;
    size_t mrow0 = (size_t)blockIdx.x * 128 + wid * 32;

    bf16x8 ah[2][4];
#pragma unroll
    for (int mt = 0; mt < 2; mt++) {
        size_t row = mrow0 + mt * 16 + r16;
        bool ok = row < N_NODES;
#pragma unroll
        for (int ks = 0; ks < 4; ks++) {
            if (ok)
                ah[mt][ks] = *reinterpret_cast<const bf16x8*>(
                    A + row * 128 + ks * 32 + kq * 8);
            else
                ah[mt][ks] = (bf16x8){0, 0, 0, 0, 0, 0, 0, 0};
        }
    }

    f32x4 acc[2][8];
#pragma unroll
    for (int mt = 0; mt < 2; mt++)
#pragma unroll
        for (int nt = 0; nt < 8; nt++) acc[mt][nt] = (f32x4){0.f, 0.f, 0.f, 0.f};

#pragma unroll
    for (int nt = 0; nt < 8; nt++) {
        const unsigned short* pbh = Fh + ((size_t)nt * 4 * 64 + lane) * 8;
        const unsigned short* pbl = Fl + ((size_t)nt * 4 * 64 + lane) * 8;
        bf16x8 bh[4], bl[4];
#pragma unroll
        for (int ks = 0; ks < 4; ks++) {
            bh[ks] = *reinterpret_cast<const bf16x8*>(pbh + ks * 512);
            bl[ks] = *reinterpret_cast<const bf16x8*>(pbl + ks * 512);
        }
#pragma unroll
        for (int mt = 0; mt < 2; mt++)
#pragma unroll
            for (int ks = 0; ks < 4; ks++) {
                acc[mt][nt] = __builtin_amdgcn_mfma_f32_16x16x32_bf16(ah[mt][ks], bl[ks],
                                                                     acc[mt][nt], 0, 0, 0);
                acc[mt][nt] = __builtin_amdgcn_mfma_f32_16x16x32_bf16(ah[mt][ks], bh[ks],
                                                                     acc[mt][nt], 0, 0, 0);
            }
    }

#pragma unroll
    for (int mt = 0; mt < 2; mt++)
#pragma unroll
        for (int nt = 0; nt < 8; nt++)
#pragma unroll
            for (int r = 0; r < 4; r++) {
                size_t row = mrow0 + mt * 16 + kq * 4 + r;
                Cb[row * 128 + nt * 16 + r16] = f2bf(acc[mt][nt][r]);
            }
}

// ------ fused K=512 encoder GEMM (pre-BN'd bf16 A) + pool, A-prefetch pipeline ---
__global__ __launch_bounds__(256, 4) void k_enc_pool(
    const unsigned short* __restrict__ Ub0, const unsigned short* __restrict__ Ub1,
    const unsigned short* __restrict__ Ub2, const unsigned short* __restrict__ Ub3,
    const unsigned short* __restrict__ Fh, const unsigned short* __restrict__ Fl,
    const float* __restrict__ encB, const int* __restrict__ batch,
    float* __restrict__ psum) {
    int lane = threadIdx.x & 63;
    int wid = threadIdx.x >> 6;
    int r16 = lane & 15, kq = lane >> 4;
    size_t brow0 = (size_t)blockIdx.x * 128;
    size_t mrow0 = brow0 + wid * 32;
    int colOff = blockIdx.y * 128;
    int ntBase = blockIdx.y * 8;

    __shared__ int batch_lds[128];
    if (threadIdx.x < 128) {
        size_t row = brow0 + threadIdx.x;
        batch_lds[threadIdx.x] = (row < N_NODES) ? batch[row] : -1;
    }
    __syncthreads();

    f32x4 acc[2][8];
#pragma unroll
    for (int mt = 0; mt < 2; mt++)
#pragma unroll
        for (int nt = 0; nt < 8; nt++) acc[mt][nt] = (f32x4){0.f, 0.f, 0.f, 0.f};

    const unsigned short* Ubs[4] = {Ub0, Ub1, Ub2, Ub3};
    bf16x8 ah[2][4];
    // prologue: load layer-0 A-frags
#pragma unroll
    for (int mt = 0; mt < 2; mt++) {
        size_t row = mrow0 + mt * 16 + r16;
        bool ok = row < N_NODES;
#pragma unroll
        for (int ks = 0; ks < 4; ks++)
            ah[mt][ks] = ok ? *reinterpret_cast<const bf16x8*>(
                                  Ub0 + row * 128 + ks * 32 + kq * 8)
                            : (bf16x8){0, 0, 0, 0, 0, 0, 0, 0};
    }

#pragma unroll 1
    for (int l = 0; l < 4; l++) {
        // prefetch next layer's A-frags while current layer computes
        bf16x8 ahn[2][4];
        if (l < 3) {
            const unsigned short* Un = Ubs[l + 1];
#pragma unroll
            for (int mt = 0; mt < 2; mt++) {
                size_t row = mrow0 + mt * 16 + r16;
                bool ok = row < N_NODES;
#pragma unroll
                for (int ks = 0; ks < 4; ks++)
                    ahn[mt][ks] = ok ? *reinterpret_cast<const bf16x8*>(
                                           Un + row * 128 + ks * 32 + kq * 8)
                                     : (bf16x8){0, 0, 0, 0, 0, 0, 0, 0};
            }
        }
        const unsigned short* Fhl = Fh + (size_t)l * 32768;
        const unsigned short* Fll = Fl + (size_t)l * 32768;
#pragma unroll
        for (int nt = 0; nt < 8; nt++) {
            const unsigned short* pbh = Fhl + ((size_t)(ntBase + nt) * 4 * 64 + lane) * 8;
            const unsigned short* pbl = Fll + ((size_t)(ntBase + nt) * 4 * 64 + lane) * 8;
            bf16x8 bh[4], bl[4];
#pragma unroll
            for (int ks = 0; ks < 4; ks++) {
                bh[ks] = *reinterpret_cast<const bf16x8*>(pbh + ks * 512);
                bl[ks] = *reinterpret_cast<const bf16x8*>(pbl + ks * 512);
            }
#pragma unroll
            for (int mt = 0; mt < 2; mt++)
#pragma unroll
                for (int ks = 0; ks < 4; ks++) {
                    acc[mt][nt] = __builtin_amdgcn_mfma_f32_16x16x32_bf16(
                        ah[mt][ks], bl[ks], acc[mt][nt], 0, 0, 0);
                    acc[mt][nt] = __builtin_amdgcn_mfma_f32_16x16x32_bf16(
                        ah[mt][ks], bh[ks], acc[mt][nt], 0, 0, 0);
                }
        }
        if (l < 3) {
#pragma unroll
            for (int mt = 0; mt < 2; mt++)
#pragma unroll
                for (int ks = 0; ks < 4; ks++) ah[mt][ks] = ahn[mt][ks];
        }
    }

    // relu(acc + encB), pads zeroed
    float bias[8];
#pragma unroll
    for (int nt = 0; nt < 8; nt++) bias[nt] = encB[colOff + nt * 16 + r16];
#pragma unroll
    for (int mt = 0; mt < 2; mt++)
#pragma unroll
        for (int r = 0; r < 4; r++) {
            bool valid = batch_lds[wid * 32 + mt * 16 + kq * 4 + r] >= 0;
#pragma unroll
            for (int nt = 0; nt < 8; nt++)
                acc[mt][nt][r] = valid ? fmaxf(acc[mt][nt][r] + bias[nt], 0.f) : 0.f;
        }

    // segment pool (batch sorted; block spans few graphs)
    int lastIdx = (int)((N_NODES - 1 - brow0) < 127 ? (N_NODES - 1 - brow0) : 127);
    int g0 = batch_lds[0];
    int g1 = batch_lds[lastIdx];
    __shared__ float sred[4][128];
    for (int g = g0; g <= g1; ++g) {
        float s[8];
#pragma unroll
        for (int nt = 0; nt < 8; nt++) s[nt] = 0.f;
#pragma unroll
        for (int mt = 0; mt < 2; mt++)
#pragma unroll
            for (int r = 0; r < 4; r++) {
                bool m = batch_lds[wid * 32 + mt * 16 + kq * 4 + r] == g;
                if (m) {
#pragma unroll
                    for (int nt = 0; nt < 8; nt++) s[nt] += acc[mt][nt][r];
                }
            }
#pragma unroll
        for (int nt = 0; nt < 8; nt++) {
            s[nt] += __shfl_xor(s[nt], 16);
            s[nt] += __shfl_xor(s[nt], 32);
        }
        if (lane < 16) {
#pragma unroll
            for (int nt = 0; nt < 8; nt++) sred[wid][nt * 16 + r16] = s[nt];
        }
        __syncthreads();
        if (threadIdx.x < 128) {
            float tot = sred[0][threadIdx.x] + sred[1][threadIdx.x] +
                        sred[2][threadIdx.x] + sred[3][threadIdx.x];
            atomicAdd(&psum[(size_t)g * ENCDIM + colOff + threadIdx.x], tot);
        }
        __syncthreads();
    }
}

// ------ aggregation: gather bf16 hw; Ub(raw bf16) <- S * hw + bias ---------------
__global__ __launch_bounds__(256) void k_agg(const unsigned short* __restrict__ hwb,
                                             const int* __restrict__ rs,
                                             const int* __restrict__ cnt,
                                             const int2* __restrict__ csr_ew,
                                             const float* __restrict__ dinv,
                                             const float4* __restrict__ bias4,
                                             unsigned short* __restrict__ Ub) {
    int n = blockIdx.x * 8 + (threadIdx.x >> 5);
    int lane = threadIdx.x & 31;
    if (n >= N_NODES) return;
    float d = dinv[n];
    float dd = d * d;
    ushort4 sb = *(const ushort4*)(hwb + (size_t)n * 128 + lane * 4);
    float4 b = bias4[lane];
    float4 acc;
    acc.x = fmaf(dd, bf2f(sb.x), b.x);
    acc.y = fmaf(dd, bf2f(sb.y), b.y);
    acc.z = fmaf(dd, bf2f(sb.z), b.z);
    acc.w = fmaf(dd, bf2f(sb.w), b.w);
    int s0 = rs[n];
    int c = cnt[n];
    int e = 0;
    for (; e + 8 <= c; e += 8) {
        int2 ee[8];
        ushort4 vv[8];
#pragma unroll
        for (int u = 0; u < 8; u++) ee[u] = csr_ew[s0 + e + u];
#pragma unroll
        for (int u = 0; u < 8; u++)
            vv[u] = *(const ushort4*)(hwb + (size_t)ee[u].x * 128 + lane * 4);
#pragma unroll
        for (int u = 0; u < 8; u++) {
            float w = __int_as_float(ee[u].y);
            acc.x = fmaf(w, bf2f(vv[u].x), acc.x);
            acc.y = fmaf(w, bf2f(vv[u].y), acc.y);
            acc.z = fmaf(w, bf2f(vv[u].z), acc.z);
            acc.w = fmaf(w, bf2f(vv[u].w), acc.w);
        }
    }
    for (; e < c; e++) {
        int2 ee = csr_ew[s0 + e];
        ushort4 v = *(const ushort4*)(hwb + (size_t)ee.x * 128 + lane * 4);
        float w = __int_as_float(ee.y);
        acc.x = fmaf(w, bf2f(v.x), acc.x);
        acc.y = fmaf(w, bf2f(v.y), acc.y);
        acc.z = fmaf(w, bf2f(v.z), acc.z);
        acc.w = fmaf(w, bf2f(v.w), acc.w);
    }
    ushort4 bv;
    bv.x = f2bf(acc.x);
    bv.y = f2bf(acc.y);
    bv.z = f2bf(acc.z);
    bv.w = f2bf(acc.w);
    *(ushort4*)(Ub + (size_t)n * 128 + lane * 4) = bv;
}

// ---------------- BN stats on raw bf16 Ub -> per-block partials (NO atomics) -----
__global__ __launch_bounds__(256) void k_bn_stats(const uint4* __restrict__ Ub4,
                                                  float* __restrict__ part_sum,
                                                  float* __restrict__ part_sq) {
    int c = threadIdx.x & 15;   // uint4 column = features 8c..8c+7
    int y = threadIdx.x >> 4;   // 16 row-groups
    float s[8], q[8];
#pragma unroll
    for (int j = 0; j < 8; j++) { s[j] = 0.f; q[j] = 0.f; }
    for (size_t n = (size_t)blockIdx.x * 16 + y; n < N_NODES;
         n += (size_t)gridDim.x * 16) {
        uint4 v = Ub4[n * 16 + c];
        float a[8];
        a[0] = bf2f(v.x & 0xffffu); a[1] = bf2f(v.x >> 16);
        a[2] = bf2f(v.y & 0xffffu); a[3] = bf2f(v.y >> 16);
        a[4] = bf2f(v.z & 0xffffu); a[5] = bf2f(v.z >> 16);
        a[6] = bf2f(v.w & 0xffffu); a[7] = bf2f(v.w >> 16);
#pragma unroll
        for (int j = 0; j < 8; j++) {
            s[j] += a[j];
            q[j] = fmaf(a[j], a[j], q[j]);
        }
    }
    __shared__ float ls[256][9], lq[256][9];  // +1 pad: no bank conflict
#pragma unroll
    for (int j = 0; j < 8; j++) {
        ls[threadIdx.x][j] = s[j];
        lq[threadIdx.x][j] = q[j];
    }
    __syncthreads();
    if (y == 0) {
#pragma unroll
        for (int yy = 1; yy < 16; yy++)
#pragma unroll
            for (int j = 0; j < 8; j++) {
                s[j] += ls[yy * 16 + c][j];
                q[j] += lq[yy * 16 + c][j];
            }
#pragma unroll
        for (int j = 0; j < 8; j++) {
            part_sum[(size_t)blockIdx.x * 128 + c * 8 + j] = s[j];
            part_sq[(size_t)blockIdx.x * 128 + c * 8 + j] = q[j];
        }
    }
}

// ------ finalize: reduce per-block partials, compute scale/shift ----------------
__global__ void k_bn_finalize(const float* __restrict__ part_sum,
                              const float* __restrict__ part_sq,
                              const float* __restrict__ gamma,
                              const float* __restrict__ beta,
                              float* __restrict__ scale, float* __restrict__ shift) {
    int f = threadIdx.x;  // 128 threads
    float s = 0.f, q = 0.f;
#pragma unroll 8
    for (int b = 0; b < BN_BLOCKS; b++) {
        s += part_sum[(size_t)b * 128 + f];
        q += part_sq[(size_t)b * 128 + f];
    }
    float mu = s * (1.0f / N_NODES);
    float var = q * (1.0f / N_NODES) - mu * mu;
    float sc = rsqrtf(var + EPS_BN) * gamma[f];
    scale[f] = sc;
    shift[f] = beta[f] - mu * sc;
}

// ------ in-place BN+ReLU on bf16 activation buffer -------
__global__ __launch_bounds__(256) void k_bnapply(uint4* __restrict__ Ub4,
                                                 const float* __restrict__ scale,
                                                 const float* __restrict__ shift) {
    size_t i = (size_t)blockIdx.x * 256 + threadIdx.x;  // NPAD*16 uint4s
    int f0 = (int)(i & 15) * 8;
    float4 sc0 = *(const float4*)&scale[f0];
    float4 sc1 = *(const float4*)&scale[f0 + 4];
    float4 sh0 = *(const float4*)&shift[f0];
    float4 sh1 = *(const float4*)&shift[f0 + 4];
    uint4 v = Ub4[i];
    float a0 = fmaxf(fmaf(bf2f(v.x & 0xffffu), sc0.x, sh0.x), 0.f);
    float a1 = fmaxf(fmaf(bf2f(v.x >> 16), sc0.y, sh0.y), 0.f);
    float a2 = fmaxf(fmaf(bf2f(v.y & 0xffffu), sc0.z, sh0.z), 0.f);
    float a3 = fmaxf(fmaf(bf2f(v.y >> 16), sc0.w, sh0.w), 0.f);
    float a4 = fmaxf(fmaf(bf2f(v.z & 0xffffu), sc1.x, sh1.x), 0.f);
    float a5 = fmaxf(fmaf(bf2f(v.z >> 16), sc1.y, sh1.y), 0.f);
    float a6 = fmaxf(fmaf(bf2f(v.w & 0xffffu), sc1.z, sh1.z), 0.f);
    float a7 = fmaxf(fmaf(bf2f(v.w >> 16), sc1.w, sh1.w), 0.f);
    uint4 o;
    o.x = (unsigned int)f2bf(a0) | ((unsigned int)f2bf(a1) << 16);
    o.y = (unsigned int)f2bf(a2) | ((unsigned int)f2bf(a3) << 16);
    o.z = (unsigned int)f2bf(a4) | ((unsigned int)f2bf(a5) << 16);
    o.w = (unsigned int)f2bf(a6) | ((unsigned int)f2bf(a7) << 16);
    Ub4[i] = o;
}

// ---------------- decoder (mean-divide folded in) ----------------
__global__ __launch_bounds__(128) void k_dec(const float* __restrict__ psum,
                                             const int* __restrict__ gcnt,
                                             const float* __restrict__ W1,
                                             const float* __restrict__ b1,
                                             const float* __restrict__ W2,
                                             const float* __restrict__ b2,
                                             float* __restrict__ out) {
    int g = blockIdx.x;
    int j = threadIdx.x;
    float inv = 1.0f / fmaxf((float)gcnt[g], 1.0f);
    const float* p = &psum[g * ENCDIM];
    float acc = b1[j];
    for (int k = 0; k < ENCDIM; k++) acc = fmaf(p[k] * inv, W1[k * 128 + j], acc);
    float h = fmaxf(acc, 0.f) * W2[j];
    for (int off = 32; off; off >>= 1) h += __shfl_down(h, off);
    __shared__ float red[2];
    if ((j & 63) == 0) red[j >> 6] = h;
    __syncthreads();
    if (j == 0) out[g] = red[0] + red[1] + b2[0];
}

extern "C" void kernel_launch(void* const* d_in, const int* in_sizes, int n_in,
                              void* d_out, int out_size, void* d_ws, size_t ws_size,
                              hipStream_t stream) {
    const float* x = (const float*)d_in[0];
    const int* ei = (const int*)d_in[1];
    const int* src = ei;
    const int* dst = ei + N_EDGES;
    const int* batch = (const int*)d_in[2];
    const float* convW = (const float*)d_in[3];
    const float* convB = (const float*)d_in[4];
    const float* gamma = (const float*)d_in[5];
    const float* beta = (const float*)d_in[6];
    const float* encW = (const float*)d_in[7];
    const float* encB = (const float*)d_in[8];
    const float* dW1 = (const float*)d_in[9];
    const float* db1 = (const float*)d_in[10];
    const float* dW2 = (const float*)d_in[11];
    const float* db2 = (const float*)d_in[12];
    float* out = (float*)d_out;

    char* w = (char*)d_ws;
    auto alloc = [&](size_t bytes) {
        char* p = w;
        w += (bytes + 255) & ~(size_t)255;
        return p;
    };
    // workspace budget ~146 MB (well within proven 221 MB envelope)
    int* cnt = (int*)alloc((size_t)N_NODES * 4);
    int* rs = (int*)alloc((size_t)N_NODES * 4);
    int* cursor = (int*)alloc((size_t)N_NODES * 4);
    int* bsums = (int*)alloc(512 * 4);
    float* dinv = (float*)alloc((size_t)N_NODES * 4);
    int2* csr_ew = (int2*)alloc((size_t)N_EDGES * 8);
    unsigned short* B = (unsigned short*)alloc((size_t)NPAD * HDIM * 2);  // hw bf16
    unsigned short* Ubf[NLAYERS];                                  // agg out (bf16)
    for (int l = 0; l < NLAYERS; l++)
        Ubf[l] = (unsigned short*)alloc((size_t)NPAD * HDIM * 2);
    unsigned short* convWfh = (unsigned short*)alloc((size_t)NLAYERS * 16384 * 2);
    unsigned short* convWfl = (unsigned short*)alloc((size_t)NLAYERS * 16384 * 2);
    unsigned short* encWfh = (unsigned short*)alloc((size_t)NLAYERS * 32768 * 2);
    unsigned short* encWfl = (unsigned short*)alloc((size_t)NLAYERS * 32768 * 2);
    float* part_sum = (float*)alloc((size_t)BN_BLOCKS * 128 * 4);
    float* part_sq = (float*)alloc((size_t)BN_BLOCKS * 128 * 4);
    float* bnscaleAll = (float*)alloc(NLAYERS * 128 * 4);
    float* bnshiftAll = (float*)alloc(NLAYERS * 128 * 4);
    int* gcnt = (int*)alloc(256 * 4);
    int* gstart = (int*)alloc(256 * 4);
    float* psum = (float*)alloc(256 * 256 * 4);

    // zero init
    hipMemsetAsync(cnt, 0, (size_t)N_NODES * 4, stream);
    hipMemsetAsync(psum, 0, 256 * 256 * 4, stream);

    // CSR build + degree normalization
    k_count<<<(N_EDGES + 1023) / 1024, 256, 0, stream>>>(dst, cnt);
    k_dinv<<<(N_NODES + 255) / 256, 256, 0, stream>>>(cnt, dinv);
    int nb = (N_NODES + 255) / 256;  // 391
    k_scan_block<<<nb, 256, 0, stream>>>(cnt, rs, bsums);
    k_scan_sums<<<1, 512, 0, stream>>>(bsums, nb);
    k_scan_add<<<nb, 256, 0, stream>>>(rs, bsums, cursor);
    k_scatter<<<(N_EDGES + 1023) / 1024, 256, 0, stream>>>(src, dst, dinv, cursor,
                                                           csr_ew);
    k_gbounds<<<1, 256, 0, stream>>>(batch, gstart, gcnt);

    // weight fragment permute + split (tiny)
    for (int l = 0; l < NLAYERS; l++) {
        k_wfrag<<<8, 256, 0, stream>>>(convW + (size_t)l * 16384, 128, 8,
                                       convWfh + (size_t)l * 16384,
                                       convWfl + (size_t)l * 16384);
        k_wfrag<<<16, 256, 0, stream>>>(encW + (size_t)l * 128 * 256, 256, 16,
                                        encWfh + (size_t)l * 32768,
                                        encWfl + (size_t)l * 32768);
    }

    for (int l = 0; l < NLAYERS; l++) {
        // hw(bf16) = h @ convW_l  (h = x fp32 for l=0; else pre-BN'd bf16 Ubf[l-1])
        if (l == 0)
            k_mfma_f32<<<NPAD / 128, 256, 0, stream>>>(
                x, convWfh + (size_t)l * 16384, convWfl + (size_t)l * 16384, B);
        else
            k_mfma_bf<<<NPAD / 128, 256, 0, stream>>>(
                Ubf[l - 1], convWfh + (size_t)l * 16384, convWfl + (size_t)l * 16384, B);
        // aggregate (bf16 gather) + bias -> Ubf[l] (raw bf16)
        k_agg<<<N_NODES / 8, 256, 0, stream>>>(B, rs, cnt, csr_ew, dinv,
                                               (const float4*)(convB + l * 128), Ubf[l]);
        // BN stats via per-block partials (no atomics), then finalize
        k_bn_stats<<<BN_BLOCKS, 256, 0, stream>>>((const uint4*)Ubf[l], part_sum,
                                                  part_sq);
        k_bn_finalize<<<1, 128, 0, stream>>>(part_sum, part_sq,
                                             gamma + l * 128, beta + l * 128,
                                             bnscaleAll + l * 128, bnshiftAll + l * 128);
        // in-place BN+ReLU on Ubf[l] (feeds next conv AND encoder)
        k_bnapply<<<NPAD * 16 / 256, 256, 0, stream>>>((uint4*)Ubf[l],
                                                       bnscaleAll + l * 128,
                                                       bnshiftAll + l * 128);
    }

    // fused K=512 encoder GEMM + bias + ReLU + segment pool
    k_enc_pool<<<dim3(NPAD / 128, 2), 256, 0, stream>>>(
        Ubf[0], Ubf[1], Ubf[2], Ubf[3], encWfh, encWfl, encB, batch, psum);
    k_dec<<<256, 128, 0, stream>>>(psum, gcnt, dW1, db1, dW2, db2, out);
}

// Round 15
// 757.447 us; speedup vs baseline: 1.4334x; 1.0981x over previous
//
#include <hip/hip_runtime.h>
#include <hip/hip_bf16.h>

#define N_NODES 100000
#define NPAD    100096   // 782 * 128
#define N_EDGES 1600000
#define HDIM 128
#define NLAYERS 4
#define NGRAPH 256
#define ENCDIM 256
#define EPS_BN 1e-5f
#define BN_BLOCKS 256

typedef __attribute__((ext_vector_type(8))) short bf16x8;
typedef __attribute__((ext_vector_type(4))) float f32x4;

__device__ __forceinline__ unsigned short f2bf(float v) {
    unsigned int u = __float_as_uint(v);
    u += 0x7FFFu + ((u >> 16) & 1u);
    return (unsigned short)(u >> 16);
}
__device__ __forceinline__ float bf2f(unsigned int lo16) {
    return __uint_as_float(lo16 << 16);
}

// ---------------- CSR build ----------------
// 4 edges/thread: 4 independent atomic chains in flight (latency hiding)
__global__ void k_count(const int* __restrict__ dst, int* __restrict__ cnt) {
    int base = blockIdx.x * 1024 + threadIdx.x;
#pragma unroll
    for (int u = 0; u < 4; u++) {
        int e = base + u * 256;
        if (e < N_EDGES) atomicAdd(&cnt[dst[e]], 1);
    }
}

__global__ void k_dinv(const int* __restrict__ cnt, float* __restrict__ dinv) {
    int n = blockIdx.x * 256 + threadIdx.x;
    if (n < N_NODES) dinv[n] = rsqrtf((float)cnt[n] + 1.0f);
}

__global__ void k_scan_block(const int* __restrict__ cnt, int* __restrict__ excl,
                             int* __restrict__ bsums) {
    __shared__ int s[256];
    int t = threadIdx.x;
    int i = blockIdx.x * 256 + t;
    int v = (i < N_NODES) ? cnt[i] : 0;
    s[t] = v;
    __syncthreads();
    for (int off = 1; off < 256; off <<= 1) {
        int x = 0;
        if (t >= off) x = s[t - off];
        __syncthreads();
        if (t >= off) s[t] += x;
        __syncthreads();
    }
    if (i < N_NODES) excl[i] = s[t] - v;
    if (t == 255) bsums[blockIdx.x] = s[255];
}

__global__ void k_scan_sums(int* __restrict__ bsums, int nb) {
    __shared__ int s[512];
    int t = threadIdx.x;
    int v = (t < nb) ? bsums[t] : 0;
    s[t] = v;
    __syncthreads();
    for (int off = 1; off < 512; off <<= 1) {
        int x = 0;
        if (t >= off) x = s[t - off];
        __syncthreads();
        if (t >= off) s[t] += x;
        __syncthreads();
    }
    if (t < nb) bsums[t] = s[t] - v;
}

__global__ void k_scan_add(int* __restrict__ excl, const int* __restrict__ bsums,
                           int* __restrict__ cursor) {
    int i = blockIdx.x * 256 + threadIdx.x;
    if (i < N_NODES) {
        int v = excl[i] + bsums[blockIdx.x];
        excl[i] = v;
        cursor[i] = v;
    }
}

// 4 edges/thread: batch loads, then products, then atomics, then stores
__global__ void k_scatter(const int* __restrict__ src, const int* __restrict__ dst,
                          const float* __restrict__ dinv, int* __restrict__ cursor,
                          int2* __restrict__ csr_ew) {
    int base = blockIdx.x * 1024 + threadIdx.x;
    int s[4], d[4];
    bool ok[4];
#pragma unroll
    for (int u = 0; u < 4; u++) {
        int e = base + u * 256;
        ok[u] = e < N_EDGES;
        s[u] = ok[u] ? src[e] : 0;
        d[u] = ok[u] ? dst[e] : 0;
    }
    float ww[4];
#pragma unroll
    for (int u = 0; u < 4; u++)
        if (ok[u]) ww[u] = dinv[s[u]] * dinv[d[u]];
    int p[4];
#pragma unroll
    for (int u = 0; u < 4; u++)
        if (ok[u]) p[u] = atomicAdd(&cursor[d[u]], 1);
#pragma unroll
    for (int u = 0; u < 4; u++)
        if (ok[u]) {
            int2 v;
            v.x = s[u];
            v.y = __float_as_int(ww[u]);
            csr_ew[p[u]] = v;
        }
}

// ---------------- graph bounds via binary search (batch is sorted) ----------------
__global__ void k_gbounds(const int* __restrict__ batch, int* __restrict__ gstart,
                          int* __restrict__ gcnt) {
    __shared__ int s[257];
    int g = threadIdx.x;  // 256 threads
    int lo = 0, hi = N_NODES;
    while (lo < hi) {
        int mid = (lo + hi) >> 1;
        if (batch[mid] < g) lo = mid + 1; else hi = mid;
    }
    s[g] = lo;
    if (g == 255) s[256] = N_NODES;
    __syncthreads();
    gstart[g] = s[g];
    gcnt[g] = s[g + 1] - s[g];
}

// ---------------- weight -> MFMA B-fragment order, split hi/lo ----------------
// F[((nt*4 + ks)*64 + lane)*8 + j] = W[(ks*32 + (lane>>4)*8 + j)*ldw + nt*16 + (lane&15)]
__global__ void k_wfrag(const float* __restrict__ W, int ldw, int ntiles,
                        unsigned short* __restrict__ Fh, unsigned short* __restrict__ Fl) {
    int t = blockIdx.x * 256 + threadIdx.x;
    if (t >= ntiles * 256) return;
    int lane = t & 63, ks = (t >> 6) & 3, nt = t >> 8;
    int r16 = lane & 15, kq = lane >> 4;
    unsigned short h[8], l[8];
#pragma unroll
    for (int j = 0; j < 8; j++) {
        float w = W[(size_t)(ks * 32 + kq * 8 + j) * ldw + nt * 16 + r16];
        unsigned short hh = f2bf(w);
        h[j] = hh;
        l[j] = f2bf(w - bf2f(hh));
    }
    ((ushort4*)(Fh + (size_t)t * 8))[0] = make_ushort4(h[0], h[1], h[2], h[3]);
    ((ushort4*)(Fh + (size_t)t * 8))[1] = make_ushort4(h[4], h[5], h[6], h[7]);
    ((ushort4*)(Fl + (size_t)t * 8))[0] = make_ushort4(l[0], l[1], l[2], l[3]);
    ((ushort4*)(Fl + (size_t)t * 8))[1] = make_ushort4(l[4], l[5], l[6], l[7]);
}

// ---------------- helper: load fp32 A + hi/lo split (layer-0 conv) ----------
__device__ __forceinline__ void load_a_frag(const float* __restrict__ A, size_t row,
                                            bool ok, int kq, int ks,
                                            bf16x8& hv_out, bf16x8& lv_out) {
    float4 v0 = make_float4(0.f, 0.f, 0.f, 0.f);
    float4 v1 = make_float4(0.f, 0.f, 0.f, 0.f);
    if (ok) {
        const float* pa = A + row * 128 + kq * 8 + ks * 32;
        v0 = *(const float4*)pa;
        v1 = *(const float4*)(pa + 4);
    }
    float vv[8] = {v0.x, v0.y, v0.z, v0.w, v1.x, v1.y, v1.z, v1.w};
    bf16x8 hv, lv;
#pragma unroll
    for (int j = 0; j < 8; j++) {
        unsigned short hh = f2bf(vv[j]);
        hv[j] = (short)hh;
        lv[j] = (short)f2bf(vv[j] - bf2f(hh));
    }
    hv_out = hv;
    lv_out = lv;
}

// ------ layer-0 conv GEMM: split-bf16 MFMA, fp32 A (= x), bf16 C out -------
__global__ __launch_bounds__(256) void k_mfma_f32(const float* __restrict__ A,
                                                  const unsigned short* __restrict__ Fh,
                                                  const unsigned short* __restrict__ Fl,
                                                  unsigned short* __restrict__ Cb) {
    int lane = threadIdx.x & 63;
    int wid = threadIdx.x >> 6;
    int r16 = lane & 15, kq = lane >> 4;
    size_t mrow0 = (size_t)blockIdx.x * 128 + wid * 32;

    bf16x8 ah[2][4], al[2][4];
#pragma unroll
    for (int mt = 0; mt < 2; mt++) {
        size_t row = mrow0 + mt * 16 + r16;
        bool ok = row < N_NODES;
#pragma unroll
        for (int ks = 0; ks < 4; ks++)
            load_a_frag(A, row, ok, kq, ks, ah[mt][ks], al[mt][ks]);
    }

    f32x4 acc[2][8];
#pragma unroll
    for (int mt = 0; mt < 2; mt++)
#pragma unroll
        for (int nt = 0; nt < 8; nt++) acc[mt][nt] = (f32x4){0.f, 0.f, 0.f, 0.f};

#pragma unroll
    for (int nt = 0; nt < 8; nt++) {
        const unsigned short* pbh = Fh + ((size_t)nt * 4 * 64 + lane) * 8;
        const unsigned short* pbl = Fl + ((size_t)nt * 4 * 64 + lane) * 8;
        bf16x8 bh[4], bl[4];
#pragma unroll
        for (int ks = 0; ks < 4; ks++) {
            bh[ks] = *reinterpret_cast<const bf16x8*>(pbh + ks * 512);
            bl[ks] = *reinterpret_cast<const bf16x8*>(pbl + ks * 512);
        }
#pragma unroll
        for (int mt = 0; mt < 2; mt++)
#pragma unroll
            for (int ks = 0; ks < 4; ks++) {
                acc[mt][nt] = __builtin_amdgcn_mfma_f32_16x16x32_bf16(ah[mt][ks], bl[ks],
                                                                     acc[mt][nt], 0, 0, 0);
                acc[mt][nt] = __builtin_amdgcn_mfma_f32_16x16x32_bf16(al[mt][ks], bh[ks],
                                                                     acc[mt][nt], 0, 0, 0);
                acc[mt][nt] = __builtin_amdgcn_mfma_f32_16x16x32_bf16(ah[mt][ks], bh[ks],
                                                                     acc[mt][nt], 0, 0, 0);
            }
    }

#pragma unroll
    for (int mt = 0; mt < 2; mt++)
#pragma unroll
        for (int nt = 0; nt < 8; nt++)
#pragma unroll
            for (int r = 0; r < 4; r++) {
                size_t row = mrow0 + mt * 16 + kq * 4 + r;
                Cb[row * 128 + nt * 16 + r16] = f2bf(acc[mt][nt][r]);
            }
}

// ------ layer>=1 conv GEMM: single-bf16 A (pre-BN'd Ubf), split-bf16 W ----------
__global__ __launch_bounds__(256) void k_mfma_bf(const unsigned short* __restrict__ A,
                                                 const unsigned short* __restrict__ Fh,
                                                 const unsigned short* __restrict__ Fl,
                                                 unsigned short* __restrict__ Cb) {
    int lane = threadIdx.x & 63;
    int wid = threadIdx.x >> 6;
    int r16 = lane & 15, kq = lane >> 4;
    size_t mrow0 = (size_t)blockIdx.x * 128 + wid * 32;

    bf16x8 ah[2][4];
#pragma unroll
    for (int mt = 0; mt < 2; mt++) {
        size_t row = mrow0 + mt * 16 + r16;
        bool ok = row < N_NODES;
#pragma unroll
        for (int ks = 0; ks < 4; ks++) {
            if (ok)
                ah[mt][ks] = *reinterpret_cast<const bf16x8*>(
                    A + row * 128 + ks * 32 + kq * 8);
            else
                ah[mt][ks] = (bf16x8){0, 0, 0, 0, 0, 0, 0, 0};
        }
    }

    f32x4 acc[2][8];
#pragma unroll
    for (int mt = 0; mt < 2; mt++)
#pragma unroll
        for (int nt = 0; nt < 8; nt++) acc[mt][nt] = (f32x4){0.f, 0.f, 0.f, 0.f};

#pragma unroll
    for (int nt = 0; nt < 8; nt++) {
        const unsigned short* pbh = Fh + ((size_t)nt * 4 * 64 + lane) * 8;
        const unsigned short* pbl = Fl + ((size_t)nt * 4 * 64 + lane) * 8;
        bf16x8 bh[4], bl[4];
#pragma unroll
        for (int ks = 0; ks < 4; ks++) {
            bh[ks] = *reinterpret_cast<const bf16x8*>(pbh + ks * 512);
            bl[ks] = *reinterpret_cast<const bf16x8*>(pbl + ks * 512);
        }
#pragma unroll
        for (int mt = 0; mt < 2; mt++)
#pragma unroll
            for (int ks = 0; ks < 4; ks++) {
                acc[mt][nt] = __builtin_amdgcn_mfma_f32_16x16x32_bf16(ah[mt][ks], bl[ks],
                                                                     acc[mt][nt], 0, 0, 0);
                acc[mt][nt] = __builtin_amdgcn_mfma_f32_16x16x32_bf16(ah[mt][ks], bh[ks],
                                                                     acc[mt][nt], 0, 0, 0);
            }
    }

#pragma unroll
    for (int mt = 0; mt < 2; mt++)
#pragma unroll
        for (int nt = 0; nt < 8; nt++)
#pragma unroll
            for (int r = 0; r < 4; r++) {
                size_t row = mrow0 + mt * 16 + kq * 4 + r;
                Cb[row * 128 + nt * 16 + r16] = f2bf(acc[mt][nt][r]);
            }
}

// ------ fused K=512 encoder GEMM (pre-BN'd bf16 A, split-bf16 W) + pool ----------
// (R11/R13 form: plain launch bounds, no prefetch — 92 µs measured; the
//  launch_bounds(256,4)+prefetch variant spilled to scratch and ran 155 µs)
__global__ __launch_bounds__(256) void k_enc_pool(
    const unsigned short* __restrict__ Ub0, const unsigned short* __restrict__ Ub1,
    const unsigned short* __restrict__ Ub2, const unsigned short* __restrict__ Ub3,
    const unsigned short* __restrict__ Fh, const unsigned short* __restrict__ Fl,
    const float* __restrict__ encB, const int* __restrict__ batch,
    float* __restrict__ psum) {
    int lane = threadIdx.x & 63;
    int wid = threadIdx.x >> 6;
    int r16 = lane & 15, kq = lane >> 4;
    size_t brow0 = (size_t)blockIdx.x * 128;
    size_t mrow0 = brow0 + wid * 32;
    int colOff = blockIdx.y * 128;
    int ntBase = blockIdx.y * 8;

    __shared__ int batch_lds[128];
    if (threadIdx.x < 128) {
        size_t row = brow0 + threadIdx.x;
        batch_lds[threadIdx.x] = (row < N_NODES) ? batch[row] : -1;
    }
    __syncthreads();

    f32x4 acc[2][8];
#pragma unroll
    for (int mt = 0; mt < 2; mt++)
#pragma unroll
        for (int nt = 0; nt < 8; nt++) acc[mt][nt] = (f32x4){0.f, 0.f, 0.f, 0.f};

    const unsigned short* Ubs[4] = {Ub0, Ub1, Ub2, Ub3};
#pragma unroll 1
    for (int l = 0; l < 4; l++) {
        const unsigned short* Ub = Ubs[l];
        bf16x8 ah[2][4];
#pragma unroll
        for (int mt = 0; mt < 2; mt++) {
            size_t row = mrow0 + mt * 16 + r16;
            bool ok = row < N_NODES;
#pragma unroll
            for (int ks = 0; ks < 4; ks++) {
                if (ok)
                    ah[mt][ks] = *reinterpret_cast<const bf16x8*>(
                        Ub + row * 128 + ks * 32 + kq * 8);
                else
                    ah[mt][ks] = (bf16x8){0, 0, 0, 0, 0, 0, 0, 0};
            }
        }
        const unsigned short* Fhl = Fh + (size_t)l * 32768;
        const unsigned short* Fll = Fl + (size_t)l * 32768;
#pragma unroll
        for (int nt = 0; nt < 8; nt++) {
            const unsigned short* pbh = Fhl + ((size_t)(ntBase + nt) * 4 * 64 + lane) * 8;
            const unsigned short* pbl = Fll + ((size_t)(ntBase + nt) * 4 * 64 + lane) * 8;
            bf16x8 bh[4], bl[4];
#pragma unroll
            for (int ks = 0; ks < 4; ks++) {
                bh[ks] = *reinterpret_cast<const bf16x8*>(pbh + ks * 512);
                bl[ks] = *reinterpret_cast<const bf16x8*>(pbl + ks * 512);
            }
#pragma unroll
            for (int mt = 0; mt < 2; mt++)
#pragma unroll
                for (int ks = 0; ks < 4; ks++) {
                    acc[mt][nt] = __builtin_amdgcn_mfma_f32_16x16x32_bf16(
                        ah[mt][ks], bl[ks], acc[mt][nt], 0, 0, 0);
                    acc[mt][nt] = __builtin_amdgcn_mfma_f32_16x16x32_bf16(
                        ah[mt][ks], bh[ks], acc[mt][nt], 0, 0, 0);
                }
        }
    }

    // relu(acc + encB), pads zeroed
    float bias[8];
#pragma unroll
    for (int nt = 0; nt < 8; nt++) bias[nt] = encB[colOff + nt * 16 + r16];
#pragma unroll
    for (int mt = 0; mt < 2; mt++)
#pragma unroll
        for (int r = 0; r < 4; r++) {
            bool valid = batch_lds[wid * 32 + mt * 16 + kq * 4 + r] >= 0;
#pragma unroll
            for (int nt = 0; nt < 8; nt++)
                acc[mt][nt][r] = valid ? fmaxf(acc[mt][nt][r] + bias[nt], 0.f) : 0.f;
        }

    // segment pool (batch sorted; block spans few graphs)
    int lastIdx = (int)((N_NODES - 1 - brow0) < 127 ? (N_NODES - 1 - brow0) : 127);
    int g0 = batch_lds[0];
    int g1 = batch_lds[lastIdx];
    __shared__ float sred[4][128];
    for (int g = g0; g <= g1; ++g) {
        float s[8];
#pragma unroll
        for (int nt = 0; nt < 8; nt++) s[nt] = 0.f;
#pragma unroll
        for (int mt = 0; mt < 2; mt++)
#pragma unroll
            for (int r = 0; r < 4; r++) {
                bool m = batch_lds[wid * 32 + mt * 16 + kq * 4 + r] == g;
                if (m) {
#pragma unroll
                    for (int nt = 0; nt < 8; nt++) s[nt] += acc[mt][nt][r];
                }
            }
#pragma unroll
        for (int nt = 0; nt < 8; nt++) {
            s[nt] += __shfl_xor(s[nt], 16);
            s[nt] += __shfl_xor(s[nt], 32);
        }
        if (lane < 16) {
#pragma unroll
            for (int nt = 0; nt < 8; nt++) sred[wid][nt * 16 + r16] = s[nt];
        }
        __syncthreads();
        if (threadIdx.x < 128) {
            float tot = sred[0][threadIdx.x] + sred[1][threadIdx.x] +
                        sred[2][threadIdx.x] + sred[3][threadIdx.x];
            atomicAdd(&psum[(size_t)g * ENCDIM + colOff + threadIdx.x], tot);
        }
        __syncthreads();
    }
}

// ------ aggregation: gather bf16 hw; Ub(raw bf16) <- S * hw + bias ---------------
__global__ __launch_bounds__(256) void k_agg(const unsigned short* __restrict__ hwb,
                                             const int* __restrict__ rs,
                                             const int* __restrict__ cnt,
                                             const int2* __restrict__ csr_ew,
                                             const float* __restrict__ dinv,
                                             const float4* __restrict__ bias4,
                                             unsigned short* __restrict__ Ub) {
    int n = blockIdx.x * 8 + (threadIdx.x >> 5);
    int lane = threadIdx.x & 31;
    if (n >= N_NODES) return;
    float d = dinv[n];
    float dd = d * d;
    ushort4 sb = *(const ushort4*)(hwb + (size_t)n * 128 + lane * 4);
    float4 b = bias4[lane];
    float4 acc;
    acc.x = fmaf(dd, bf2f(sb.x), b.x);
    acc.y = fmaf(dd, bf2f(sb.y), b.y);
    acc.z = fmaf(dd, bf2f(sb.z), b.z);
    acc.w = fmaf(dd, bf2f(sb.w), b.w);
    int s0 = rs[n];
    int c = cnt[n];
    int e = 0;
    for (; e + 8 <= c; e += 8) {
        int2 ee[8];
        ushort4 vv[8];
#pragma unroll
        for (int u = 0; u < 8; u++) ee[u] = csr_ew[s0 + e + u];
#pragma unroll
        for (int u = 0; u < 8; u++)
            vv[u] = *(const ushort4*)(hwb + (size_t)ee[u].x * 128 + lane * 4);
#pragma unroll
        for (int u = 0; u < 8; u++) {
            float w = __int_as_float(ee[u].y);
            acc.x = fmaf(w, bf2f(vv[u].x), acc.x);
            acc.y = fmaf(w, bf2f(vv[u].y), acc.y);
            acc.z = fmaf(w, bf2f(vv[u].z), acc.z);
            acc.w = fmaf(w, bf2f(vv[u].w), acc.w);
        }
    }
    for (; e < c; e++) {
        int2 ee = csr_ew[s0 + e];
        ushort4 v = *(const ushort4*)(hwb + (size_t)ee.x * 128 + lane * 4);
        float w = __int_as_float(ee.y);
        acc.x = fmaf(w, bf2f(v.x), acc.x);
        acc.y = fmaf(w, bf2f(v.y), acc.y);
        acc.z = fmaf(w, bf2f(v.z), acc.z);
        acc.w = fmaf(w, bf2f(v.w), acc.w);
    }
    ushort4 bv;
    bv.x = f2bf(acc.x);
    bv.y = f2bf(acc.y);
    bv.z = f2bf(acc.z);
    bv.w = f2bf(acc.w);
    *(ushort4*)(Ub + (size_t)n * 128 + lane * 4) = bv;
}

// ---------------- BN stats on raw bf16 Ub -> per-block partials (NO atomics) -----
__global__ __launch_bounds__(256) void k_bn_stats(const uint4* __restrict__ Ub4,
                                                  float* __restrict__ part_sum,
                                                  float* __restrict__ part_sq) {
    int c = threadIdx.x & 15;   // uint4 column = features 8c..8c+7
    int y = threadIdx.x >> 4;   // 16 row-groups
    float s[8], q[8];
#pragma unroll
    for (int j = 0; j < 8; j++) { s[j] = 0.f; q[j] = 0.f; }
    for (size_t n = (size_t)blockIdx.x * 16 + y; n < N_NODES;
         n += (size_t)gridDim.x * 16) {
        uint4 v = Ub4[n * 16 + c];
        float a[8];
        a[0] = bf2f(v.x & 0xffffu); a[1] = bf2f(v.x >> 16);
        a[2] = bf2f(v.y & 0xffffu); a[3] = bf2f(v.y >> 16);
        a[4] = bf2f(v.z & 0xffffu); a[5] = bf2f(v.z >> 16);
        a[6] = bf2f(v.w & 0xffffu); a[7] = bf2f(v.w >> 16);
#pragma unroll
        for (int j = 0; j < 8; j++) {
            s[j] += a[j];
            q[j] = fmaf(a[j], a[j], q[j]);
        }
    }
    __shared__ float ls[256][9], lq[256][9];  // +1 pad: no bank conflict
#pragma unroll
    for (int j = 0; j < 8; j++) {
        ls[threadIdx.x][j] = s[j];
        lq[threadIdx.x][j] = q[j];
    }
    __syncthreads();
    if (y == 0) {
#pragma unroll
        for (int yy = 1; yy < 16; yy++)
#pragma unroll
            for (int j = 0; j < 8; j++) {
                s[j] += ls[yy * 16 + c][j];
                q[j] += lq[yy * 16 + c][j];
            }
#pragma unroll
        for (int j = 0; j < 8; j++) {
            part_sum[(size_t)blockIdx.x * 128 + c * 8 + j] = s[j];
            part_sq[(size_t)blockIdx.x * 128 + c * 8 + j] = q[j];
        }
    }
}

// ------ finalize: reduce per-block partials, compute scale/shift ----------------
__global__ void k_bn_finalize(const float* __restrict__ part_sum,
                              const float* __restrict__ part_sq,
                              const float* __restrict__ gamma,
                              const float* __restrict__ beta,
                              float* __restrict__ scale, float* __restrict__ shift) {
    int f = threadIdx.x;  // 128 threads
    float s = 0.f, q = 0.f;
#pragma unroll 8
    for (int b = 0; b < BN_BLOCKS; b++) {
        s += part_sum[(size_t)b * 128 + f];
        q += part_sq[(size_t)b * 128 + f];
    }
    float mu = s * (1.0f / N_NODES);
    float var = q * (1.0f / N_NODES) - mu * mu;
    float sc = rsqrtf(var + EPS_BN) * gamma[f];
    scale[f] = sc;
    shift[f] = beta[f] - mu * sc;
}

// ------ in-place BN+ReLU on bf16 activation buffer -------
__global__ __launch_bounds__(256) void k_bnapply(uint4* __restrict__ Ub4,
                                                 const float* __restrict__ scale,
                                                 const float* __restrict__ shift) {
    size_t i = (size_t)blockIdx.x * 256 + threadIdx.x;  // NPAD*16 uint4s
    int f0 = (int)(i & 15) * 8;
    float4 sc0 = *(const float4*)&scale[f0];
    float4 sc1 = *(const float4*)&scale[f0 + 4];
    float4 sh0 = *(const float4*)&shift[f0];
    float4 sh1 = *(const float4*)&shift[f0 + 4];
    uint4 v = Ub4[i];
    float a0 = fmaxf(fmaf(bf2f(v.x & 0xffffu), sc0.x, sh0.x), 0.f);
    float a1 = fmaxf(fmaf(bf2f(v.x >> 16), sc0.y, sh0.y), 0.f);
    float a2 = fmaxf(fmaf(bf2f(v.y & 0xffffu), sc0.z, sh0.z), 0.f);
    float a3 = fmaxf(fmaf(bf2f(v.y >> 16), sc0.w, sh0.w), 0.f);
    float a4 = fmaxf(fmaf(bf2f(v.z & 0xffffu), sc1.x, sh1.x), 0.f);
    float a5 = fmaxf(fmaf(bf2f(v.z >> 16), sc1.y, sh1.y), 0.f);
    float a6 = fmaxf(fmaf(bf2f(v.w & 0xffffu), sc1.z, sh1.z), 0.f);
    float a7 = fmaxf(fmaf(bf2f(v.w >> 16), sc1.w, sh1.w), 0.f);
    uint4 o;
    o.x = (unsigned int)f2bf(a0) | ((unsigned int)f2bf(a1) << 16);
    o.y = (unsigned int)f2bf(a2) | ((unsigned int)f2bf(a3) << 16);
    o.z = (unsigned int)f2bf(a4) | ((unsigned int)f2bf(a5) << 16);
    o.w = (unsigned int)f2bf(a6) | ((unsigned int)f2bf(a7) << 16);
    Ub4[i] = o;
}

// ---------------- decoder (mean-divide folded in) ----------------
__global__ __launch_bounds__(128) void k_dec(const float* __restrict__ psum,
                                             const int* __restrict__ gcnt,
                                             const float* __restrict__ W1,
                                             const float* __restrict__ b1,
                                             const float* __restrict__ W2,
                                             const float* __restrict__ b2,
                                             float* __restrict__ out) {
    int g = blockIdx.x;
    int j = threadIdx.x;
    float inv = 1.0f / fmaxf((float)gcnt[g], 1.0f);
    const float* p = &psum[g * ENCDIM];
    float acc = b1[j];
    for (int k = 0; k < ENCDIM; k++) acc = fmaf(p[k] * inv, W1[k * 128 + j], acc);
    float h = fmaxf(acc, 0.f) * W2[j];
    for (int off = 32; off; off >>= 1) h += __shfl_down(h, off);
    __shared__ float red[2];
    if ((j & 63) == 0) red[j >> 6] = h;
    __syncthreads();
    if (j == 0) out[g] = red[0] + red[1] + b2[0];
}

extern "C" void kernel_launch(void* const* d_in, const int* in_sizes, int n_in,
                              void* d_out, int out_size, void* d_ws, size_t ws_size,
                              hipStream_t stream) {
    const float* x = (const float*)d_in[0];
    const int* ei = (const int*)d_in[1];
    const int* src = ei;
    const int* dst = ei + N_EDGES;
    const int* batch = (const int*)d_in[2];
    const float* convW = (const float*)d_in[3];
    const float* convB = (const float*)d_in[4];
    const float* gamma = (const float*)d_in[5];
    const float* beta = (const float*)d_in[6];
    const float* encW = (const float*)d_in[7];
    const float* encB = (const float*)d_in[8];
    const float* dW1 = (const float*)d_in[9];
    const float* db1 = (const float*)d_in[10];
    const float* dW2 = (const float*)d_in[11];
    const float* db2 = (const float*)d_in[12];
    float* out = (float*)d_out;

    char* w = (char*)d_ws;
    auto alloc = [&](size_t bytes) {
        char* p = w;
        w += (bytes + 255) & ~(size_t)255;
        return p;
    };
    // workspace budget ~146 MB (well within proven 221 MB envelope)
    int* cnt = (int*)alloc((size_t)N_NODES * 4);
    int* rs = (int*)alloc((size_t)N_NODES * 4);
    int* cursor = (int*)alloc((size_t)N_NODES * 4);
    int* bsums = (int*)alloc(512 * 4);
    float* dinv = (float*)alloc((size_t)N_NODES * 4);
    int2* csr_ew = (int2*)alloc((size_t)N_EDGES * 8);
    unsigned short* B = (unsigned short*)alloc((size_t)NPAD * HDIM * 2);  // hw bf16
    unsigned short* Ubf[NLAYERS];                                  // agg out (bf16)
    for (int l = 0; l < NLAYERS; l++)
        Ubf[l] = (unsigned short*)alloc((size_t)NPAD * HDIM * 2);
    unsigned short* convWfh = (unsigned short*)alloc((size_t)NLAYERS * 16384 * 2);
    unsigned short* convWfl = (unsigned short*)alloc((size_t)NLAYERS * 16384 * 2);
    unsigned short* encWfh = (unsigned short*)alloc((size_t)NLAYERS * 32768 * 2);
    unsigned short* encWfl = (unsigned short*)alloc((size_t)NLAYERS * 32768 * 2);
    float* part_sum = (float*)alloc((size_t)BN_BLOCKS * 128 * 4);
    float* part_sq = (float*)alloc((size_t)BN_BLOCKS * 128 * 4);
    float* bnscaleAll = (float*)alloc(NLAYERS * 128 * 4);
    float* bnshiftAll = (float*)alloc(NLAYERS * 128 * 4);
    int* gcnt = (int*)alloc(256 * 4);
    int* gstart = (int*)alloc(256 * 4);
    float* psum = (float*)alloc(256 * 256 * 4);

    // zero init
    hipMemsetAsync(cnt, 0, (size_t)N_NODES * 4, stream);
    hipMemsetAsync(psum, 0, 256 * 256 * 4, stream);

    // CSR build + degree normalization
    k_count<<<(N_EDGES + 1023) / 1024, 256, 0, stream>>>(dst, cnt);
    k_dinv<<<(N_NODES + 255) / 256, 256, 0, stream>>>(cnt, dinv);
    int nb = (N_NODES + 255) / 256;  // 391
    k_scan_block<<<nb, 256, 0, stream>>>(cnt, rs, bsums);
    k_scan_sums<<<1, 512, 0, stream>>>(bsums, nb);
    k_scan_add<<<nb, 256, 0, stream>>>(rs, bsums, cursor);
    k_scatter<<<(N_EDGES + 1023) / 1024, 256, 0, stream>>>(src, dst, dinv, cursor,
                                                           csr_ew);
    k_gbounds<<<1, 256, 0, stream>>>(batch, gstart, gcnt);

    // weight fragment permute + split (tiny)
    for (int l = 0; l < NLAYERS; l++) {
        k_wfrag<<<8, 256, 0, stream>>>(convW + (size_t)l * 16384, 128, 8,
                                       convWfh + (size_t)l * 16384,
                                       convWfl + (size_t)l * 16384);
        k_wfrag<<<16, 256, 0, stream>>>(encW + (size_t)l * 128 * 256, 256, 16,
                                        encWfh + (size_t)l * 32768,
                                        encWfl + (size_t)l * 32768);
    }

    for (int l = 0; l < NLAYERS; l++) {
        // hw(bf16) = h @ convW_l  (h = x fp32 for l=0; else pre-BN'd bf16 Ubf[l-1])
        if (l == 0)
            k_mfma_f32<<<NPAD / 128, 256, 0, stream>>>(
                x, convWfh + (size_t)l * 16384, convWfl + (size_t)l * 16384, B);
        else
            k_mfma_bf<<<NPAD / 128, 256, 0, stream>>>(
                Ubf[l - 1], convWfh + (size_t)l * 16384, convWfl + (size_t)l * 16384, B);
        // aggregate (bf16 gather) + bias -> Ubf[l] (raw bf16)
        k_agg<<<N_NODES / 8, 256, 0, stream>>>(B, rs, cnt, csr_ew, dinv,
                                               (const float4*)(convB + l * 128), Ubf[l]);
        // BN stats via per-block partials (no atomics), then finalize
        k_bn_stats<<<BN_BLOCKS, 256, 0, stream>>>((const uint4*)Ubf[l], part_sum,
                                                  part_sq);
        k_bn_finalize<<<1, 128, 0, stream>>>(part_sum, part_sq,
                                             gamma + l * 128, beta + l * 128,
                                             bnscaleAll + l * 128, bnshiftAll + l * 128);
        // in-place BN+ReLU on Ubf[l] (feeds next conv AND encoder)
        k_bnapply<<<NPAD * 16 / 256, 256, 0, stream>>>((uint4*)Ubf[l],
                                                       bnscaleAll + l * 128,
                                                       bnshiftAll + l * 128);
    }

    // fused K=512 encoder GEMM + bias + ReLU + segment pool
    k_enc_pool<<<dim3(NPAD / 128, 2), 256, 0, stream>>>(
        Ubf[0], Ubf[1], Ubf[2], Ubf[3], encWfh, encWfl, encB, batch, psum);
    k_dec<<<256, 128, 0, stream>>>(psum, gcnt, dW1, db1, dW2, db2, out);
}